// Round 15
// baseline (534.748 us; speedup 1.0000x reference)
//
#include <hip/hip_runtime.h>

#define NN 50000
#define DD 128
#define HH 8
#define EE 1600000
#define LL 2

typedef unsigned short u16;
typedef __attribute__((ext_vector_type(8))) __bf16 bf16x8;
typedef __attribute__((ext_vector_type(4))) float f32x4;
typedef __attribute__((ext_vector_type(2))) float f32x2;

__device__ __forceinline__ float bf2f(u16 u){
    return __uint_as_float(((unsigned int)u) << 16);
}
__device__ __forceinline__ u16 f2bf(float f){
    unsigned int x = __float_as_uint(f);
    x = x + 0x7fff + ((x >> 16) & 1);   // round-to-nearest-even
    return (u16)(x >> 16);
}

// async global->LDS, 16B per lane, linear dest (wave base + lane*16)
__device__ __forceinline__ void async16(const u16* g, u16* l){
    __builtin_amdgcn_global_load_lds(
        (const __attribute__((address_space(1))) unsigned int*)(const void*)g,
        (__attribute__((address_space(3))) unsigned int*)(void*)l, 16, 0, 0);
}

// ---------------- mega-prep: count | f2b4 | qkvpack | wprep in ONE launch ----------------
#define FILL_SUB 128
#define PREP_BLOCKS (1024 + 6250 + 384 + 768)

__global__ __launch_bounds__(256) void prep_kernel(
        const int* __restrict__ dst, int* __restrict__ cnt,
        const float* __restrict__ h_in, u16* __restrict__ hb,
        const float* __restrict__ Wq, const float* __restrict__ Wk, const float* __restrict__ Wv,
        const float* __restrict__ bq, const float* __restrict__ bk, const float* __restrict__ bv,
        u16* __restrict__ WtQKV, float* __restrict__ bQKV,
        const float* __restrict__ Wo, const float* __restrict__ W1, const float* __restrict__ W2,
        u16* __restrict__ WtO, u16* __restrict__ WtF1, u16* __restrict__ WtF2){
    int b = blockIdx.x;
    if (b < 1024){
        int slice = b & 7;
        int sub = b >> 3;
        int lo = slice * (NN / 8), hi = lo + (NN / 8);
        for (int e = sub * 256 + threadIdx.x; e < EE; e += FILL_SUB * 256){
            int d = dst[e];
            if (d >= lo && d < hi) atomicAdd(&cnt[d], 1);
        }
        return;
    }
    b -= 1024;
    if (b < 6250){
        int i = b * 256 + threadIdx.x;
        if (i < NN * DD / 4){
            float4 v = ((const float4*)h_in)[i];
            ushort4 o;
            o.x = f2bf(v.x); o.y = f2bf(v.y); o.z = f2bf(v.z); o.w = f2bf(v.w);
            ((ushort4*)hb)[i] = o;
        }
        return;
    }
    b -= 6250;
    if (b < 384){
        int l = b / 192;
        int idx = (b % 192) * 256 + threadIdx.x;
        if (idx < 384 * 128){
            int n = idx >> 7, k = idx & 127;
            const float* W = (n < 128) ? Wq : (n < 256) ? Wk : Wv;
            int nc = n & 127;
            WtQKV[(size_t)l * 384 * 128 + idx] = f2bf(W[(size_t)l * 128 * 128 + k * 128 + nc]);
            if (k == 0){
                const float* bb = (n < 128) ? bq : (n < 256) ? bk : bv;
                bQKV[l * 384 + n] = bb[l * 128 + nc];
            }
        }
        return;
    }
    b -= 384;
    {
        int which = b / 256;
        int rem = b % 256;
        int l = rem / 128;
        int idx = (rem % 128) * 256 + threadIdx.x;
        const float* in; u16* out; int R, C;
        if (which == 0){ in = Wo; out = WtO; R = 128; C = 128; }
        else if (which == 1){ in = W1; out = WtF1; R = 128; C = 256; }
        else { in = W2; out = WtF2; R = 256; C = 128; }
        int total = R * C;
        if (idx < total){
            size_t mat = (size_t)l * total;
            int r = idx / C, c = idx % C;
            out[mat + (size_t)c * R + r] = f2bf(in[mat + idx]);
        }
    }
}

// ---------------- CSR scan + fill ----------------
__global__ __launch_bounds__(1024) void scan_kernel(const int* __restrict__ cnt,
                                                    int* __restrict__ offs, int* __restrict__ cur){
    __shared__ int wsum[16];
    __shared__ int carry_s;
    __shared__ int ctot_s;
    int t = threadIdx.x, lane = t & 63, w = t >> 6;
    if (t == 0){ offs[0] = 0; cur[0] = 0; carry_s = 0; }
    __syncthreads();
    const int N4 = NN / 4;
    for (int base = 0; base < N4; base += 1024){
        int i4 = base + t;
        int4 x = (i4 < N4) ? ((const int4*)cnt)[i4] : make_int4(0, 0, 0, 0);
        int s1 = x.x, s2 = s1 + x.y, s3 = s2 + x.z, s4 = s3 + x.w;
        int v = s4;
        #pragma unroll
        for (int d = 1; d < 64; d <<= 1){ int u = __shfl_up(v, d); if (lane >= d) v += u; }
        if (lane == 63) wsum[w] = v;
        __syncthreads();
        if (t < 16){
            int sv = wsum[t];
            int iv = sv;
            #pragma unroll
            for (int d = 1; d < 16; d <<= 1){ int u = __shfl_up(iv, d); if (t >= d) iv += u; }
            wsum[t] = iv - sv;
            if (t == 15) ctot_s = iv;
        }
        __syncthreads();
        int excl = carry_s + wsum[w] + (v - s4);
        if (i4 < N4){
            int o = 4 * i4;
            offs[o + 1] = excl + s1;  cur[o + 1] = excl + s1;
            offs[o + 2] = excl + s2;  cur[o + 2] = excl + s2;
            offs[o + 3] = excl + s3;  cur[o + 3] = excl + s3;
            offs[o + 4] = excl + s4;  cur[o + 4] = excl + s4;
        }
        __syncthreads();
        if (t == 0) carry_s += ctot_s;
        __syncthreads();
    }
}

__global__ __launch_bounds__(256) void fill_kernel(const int* __restrict__ src, const int* __restrict__ dst,
                                                   int* __restrict__ cur, int* __restrict__ srcs){
    int slice = blockIdx.x & 7;
    int sub = blockIdx.x >> 3;
    int lo = slice * (NN / 8), hi = lo + (NN / 8);
    for (int e = sub * 256 + threadIdx.x; e < EE; e += FILL_SUB * 256){
        int d = dst[e];
        if (d >= lo && d < hi){
            int p = atomicAdd(&cur[d], 1);
            srcs[p] = src[e];
        }
    }
}

// ================= GEMM core helpers (global_load_lds + XOR swizzle) ==========
#define BM 128
#define LDC 136

__device__ __forceinline__ void stage_tile(const u16* __restrict__ A, const u16* __restrict__ Wt,
                                           u16* As, u16* Bs, int M, int K, int m0, int n0, int k0,
                                           int w, int lane){
    int lr = lane >> 3;
    int swz = ((lane & 7) ^ lr) * 8;
    #pragma unroll
    for (int p = 0; p < 4; p++){
        int s = p * 4 + w;
        int ga = m0 + s * 8 + lr;
        if (ga >= M) ga = M - 1;
        async16(A + (size_t)ga * K + k0 + swz, As + s * 512);
        async16(Wt + (size_t)(n0 + s * 8 + lr) * K + k0 + swz, Bs + s * 512);
    }
}

__device__ __forceinline__ void mfma_tiles(const u16* As, const u16* Bs, f32x4 (&acc)[4][4],
                                           int wm, int wn, int l15, int hi){
    #pragma unroll
    for (int ks = 0; ks < 2; ks++){
        bf16x8 a[4], b[4];
        int ca = ((ks * 4 + hi) ^ (l15 & 7)) * 8;
        #pragma unroll
        for (int i = 0; i < 4; i++){
            a[i] = *(const bf16x8*)(As + (wm * 64 + i * 16 + l15) * 64 + ca);
            b[i] = *(const bf16x8*)(Bs + (wn * 64 + i * 16 + l15) * 64 + ca);
        }
        #pragma unroll
        for (int mi = 0; mi < 4; mi++)
            #pragma unroll
            for (int ni = 0; ni < 4; ni++)
                acc[mi][ni] = __builtin_amdgcn_mfma_f32_16x16x32_bf16(a[mi], b[ni], acc[mi][ni], 0, 0, 0);
    }
}

#define GEMM_LOOP(K)                                                          \
    for (int k0 = 0; k0 < (K); k0 += 64){                                     \
        __syncthreads();                                                      \
        stage_tile(A, Wt, As, Bs, M, (K), m0, n0, k0, w, lane);               \
        asm volatile("s_waitcnt vmcnt(0)" ::: "memory");                      \
        __syncthreads();                                                      \
        mfma_tiles(As, Bs, acc, wm, wn, l15, hi);                             \
    }

// QKV GEMM (layer 0 only): n0=0 -> Qb bf16, n0=128 -> Kb bf16, n0=256 -> Vb fp8 e4m3
__global__ __launch_bounds__(256) void gemm_qkv(const u16* __restrict__ A, const u16* __restrict__ Wt,
                                                const float* __restrict__ bias,
                                                u16* __restrict__ Qb, u16* __restrict__ Kb,
                                                unsigned char* __restrict__ Vb, int M){
    __shared__ __align__(16) char smem[128 * LDC * 2];
    u16* As = (u16*)smem;
    u16* Bs = As + 8192;
    u16* Cs = (u16*)smem;

    int tid = threadIdx.x;
    int m0 = blockIdx.x * BM, n0 = blockIdx.y * 128;
    int lane = tid & 63, w = tid >> 6;
    int wm = w >> 1, wn = w & 1;
    int l15 = lane & 15, hi = lane >> 4;

    f32x4 acc[4][4];
    #pragma unroll
    for (int mi = 0; mi < 4; mi++)
        #pragma unroll
        for (int ni = 0; ni < 4; ni++)
            acc[mi][ni] = (f32x4){0.f, 0.f, 0.f, 0.f};

    GEMM_LOOP(128)

    __syncthreads();
    #pragma unroll
    for (int mi = 0; mi < 4; mi++)
        #pragma unroll
        for (int ni = 0; ni < 4; ni++){
            int col = wn * 64 + ni * 16 + l15;
            float bval = bias[n0 + col];
            #pragma unroll
            for (int j = 0; j < 4; j++){
                int rl = wm * 64 + mi * 16 + hi * 4 + j;
                Cs[rl * LDC + col] = f2bf(acc[mi][ni][j] + bval);
            }
        }
    __syncthreads();
    int qrow = tid >> 4, quad = tid & 15;
    if (n0 < 256){
        u16* Tb = (n0 == 0) ? Qb : Kb;
        #pragma unroll
        for (int p = 0; p < 8; p++){
            int rl = p * 16 + qrow;
            int gr = m0 + rl;
            if (gr < M){
                uint4 v = *(const uint4*)(&Cs[rl * LDC + quad * 8]);
                *(uint4*)(Tb + (size_t)gr * 128 + quad * 8) = v;
            }
        }
    } else {
        #pragma unroll
        for (int p = 0; p < 8; p++){
            int rl = p * 16 + qrow;
            int gr = m0 + rl;
            if (gr < M){
                uint4 v = *(const uint4*)(&Cs[rl * LDC + quad * 8]);
                float f0 = bf2f((u16)(v.x & 0xffff)), f1 = bf2f((u16)(v.x >> 16));
                float f2 = bf2f((u16)(v.y & 0xffff)), f3 = bf2f((u16)(v.y >> 16));
                float f4 = bf2f((u16)(v.z & 0xffff)), f5 = bf2f((u16)(v.z >> 16));
                float f6 = bf2f((u16)(v.w & 0xffff)), f7 = bf2f((u16)(v.w >> 16));
                unsigned int w0 = __builtin_amdgcn_cvt_pk_fp8_f32(f0, f1, 0u, false);
                w0 = __builtin_amdgcn_cvt_pk_fp8_f32(f2, f3, w0, true);
                unsigned int w1 = __builtin_amdgcn_cvt_pk_fp8_f32(f4, f5, 0u, false);
                w1 = __builtin_amdgcn_cvt_pk_fp8_f32(f6, f7, w1, true);
                *(uint2*)(Vb + (size_t)gr * 128 + quad * 8) = make_uint2(w0, w1);
            }
        }
    }
}

// ================= layer tail: O-proj+LN1+FFN1+relu+FFN2+LN2 (+optional next-layer QKV) =======
// 64-row tile, 4 waves. If Qb!=null: after LN2, project h2 (kept in LDS) with WtQn -> Qb/Kb/Vb,
// replicating gemm_qkv's k-order and rounding exactly (bit-exact with the unfused chain).
__global__ __launch_bounds__(256) void tail_kernel(const u16* __restrict__ att,
                                                   const u16* __restrict__ WtO, const float* __restrict__ bo,
                                                   const u16* __restrict__ resid,
                                                   const float* __restrict__ g1, const float* __restrict__ b1v,
                                                   const u16* __restrict__ W1t, const float* __restrict__ b1f,
                                                   const u16* __restrict__ W2t, const float* __restrict__ b2f,
                                                   const float* __restrict__ g2, const float* __restrict__ b2v,
                                                   u16* __restrict__ out_bf, float* __restrict__ out_f,
                                                   const u16* __restrict__ WtQn, const float* __restrict__ bQn,
                                                   u16* __restrict__ Qb, u16* __restrict__ Kb,
                                                   unsigned char* __restrict__ Vb,
                                                   int M){
    __shared__ __align__(16) u16 h1c[8192];     // 16KB: 2 chunks [64][64] (swizzled); reused as h2c
    __shared__ __align__(16) u16 mid[16384];    // 32KB: 4 chunks [64][64] (swizzled); Cs overlay
    __shared__ __align__(16) u16 Bs[8192];      // 16KB B staging
    __shared__ float ps[2][64];
    __shared__ float pss[2][64];
    u16* AsO = mid;                             // O-proj A staging overlay (8KB)
    u16* Cs  = mid;                             // QKV epilogue overlay [64][68]

    int tid = threadIdx.x, lane = tid & 63, w = tid >> 6;
    int l15 = lane & 15, hi = lane >> 4;
    int wm = w >> 1, wn = w & 1;
    int m0 = blockIdx.x * 64;
    int lr = lane >> 3;
    int swz = ((lane & 7) ^ lr) * 8;

    // ---- O-proj ----
    f32x4 acc0[2][4];
    #pragma unroll
    for (int mi = 0; mi < 2; mi++)
        #pragma unroll
        for (int ni = 0; ni < 4; ni++)
            acc0[mi][ni] = (f32x4){0.f, 0.f, 0.f, 0.f};

    for (int kh = 0; kh < 2; kh++){
        __syncthreads();
        #pragma unroll
        for (int p = 0; p < 2; p++){
            int s = p * 4 + w;
            int ga = m0 + s * 8 + lr;
            if (ga >= M) ga = M - 1;
            async16(att + (size_t)ga * 128 + kh * 64 + swz, AsO + s * 512);
        }
        #pragma unroll
        for (int p = 0; p < 4; p++){
            int s = p * 4 + w;
            int row = s * 8 + lr;
            async16(WtO + (size_t)row * 128 + kh * 64 + swz, Bs + s * 512);
        }
        asm volatile("s_waitcnt vmcnt(0)" ::: "memory");
        __syncthreads();
        #pragma unroll
        for (int ks = 0; ks < 2; ks++){
            int ca = ((ks * 4 + hi) ^ (l15 & 7)) * 8;
            bf16x8 a[2], bb[4];
            #pragma unroll
            for (int i = 0; i < 2; i++)
                a[i] = *(const bf16x8*)(AsO + (wm * 32 + i * 16 + l15) * 64 + ca);
            #pragma unroll
            for (int i = 0; i < 4; i++)
                bb[i] = *(const bf16x8*)(Bs + (wn * 64 + i * 16 + l15) * 64 + ca);
            #pragma unroll
            for (int mi = 0; mi < 2; mi++)
                #pragma unroll
                for (int ni = 0; ni < 4; ni++)
                    acc0[mi][ni] = __builtin_amdgcn_mfma_f32_16x16x32_bf16(a[mi], bb[ni], acc0[mi][ni], 0, 0, 0);
        }
    }

    // ---- LN1 -> h1c ----
    {
        float gc[4], bc[4], bv[4];
        #pragma unroll
        for (int ni = 0; ni < 4; ni++){
            int col = wn * 64 + ni * 16 + l15;
            gc[ni] = g1[col]; bc[ni] = b1v[col]; bv[ni] = bo[col];
        }
        #pragma unroll
        for (int mi = 0; mi < 2; mi++)
            #pragma unroll
            for (int j = 0; j < 4; j++){
                int row = wm * 32 + mi * 16 + hi * 4 + j;
                int gr = m0 + row;
                float s = 0.f, ss = 0.f;
                #pragma unroll
                for (int ni = 0; ni < 4; ni++){
                    int col = wn * 64 + ni * 16 + l15;
                    float x = acc0[mi][ni][j] + bv[ni];
                    if (gr < M) x += bf2f(resid[(size_t)gr * 128 + col]);
                    acc0[mi][ni][j] = x;
                    s += x; ss += x * x;
                }
                #pragma unroll
                for (int d = 1; d < 16; d <<= 1){
                    s  += __shfl_xor(s, d);
                    ss += __shfl_xor(ss, d);
                }
                if (l15 == 0){ ps[wn][row] = s; pss[wn][row] = ss; }
            }
        __syncthreads();
        #pragma unroll
        for (int mi = 0; mi < 2; mi++)
            #pragma unroll
            for (int j = 0; j < 4; j++){
                int row = wm * 32 + mi * 16 + hi * 4 + j;
                float s = ps[0][row] + ps[1][row];
                float ss = pss[0][row] + pss[1][row];
                float mean = s * (1.f / 128.f);
                float var = ss * (1.f / 128.f) - mean * mean;
                float r = rsqrtf(var + 1e-5f);
                #pragma unroll
                for (int ni = 0; ni < 4; ni++){
                    int kcol = ni * 16 + l15;
                    float o = (acc0[mi][ni][j] - mean) * r * gc[ni] + bc[ni];
                    h1c[wn * 4096 + row * 64 + (((kcol >> 3) ^ (row & 7)) * 8 + (kcol & 7))] = f2bf(o);
                }
            }
    }

    // ---- FFN1 ----
    f32x4 acc1[2][2][4];
    #pragma unroll
    for (int nh = 0; nh < 2; nh++)
        #pragma unroll
        for (int mi = 0; mi < 2; mi++)
            #pragma unroll
            for (int ni = 0; ni < 4; ni++)
                acc1[nh][mi][ni] = (f32x4){0.f, 0.f, 0.f, 0.f};

    for (int nh = 0; nh < 2; nh++){
        for (int kh = 0; kh < 2; kh++){
            __syncthreads();
            #pragma unroll
            for (int p = 0; p < 4; p++){
                int s = p * 4 + w;
                int row = s * 8 + lr;
                async16(W1t + (size_t)(nh * 128 + row) * 128 + kh * 64 + swz, Bs + s * 512);
            }
            asm volatile("s_waitcnt vmcnt(0)" ::: "memory");
            __syncthreads();
            #pragma unroll
            for (int ks = 0; ks < 2; ks++){
                int ca = ((ks * 4 + hi) ^ (l15 & 7)) * 8;
                bf16x8 a[2], bb[4];
                #pragma unroll
                for (int i = 0; i < 2; i++)
                    a[i] = *(const bf16x8*)(h1c + kh * 4096 + (wm * 32 + i * 16 + l15) * 64 + ca);
                #pragma unroll
                for (int i = 0; i < 4; i++)
                    bb[i] = *(const bf16x8*)(Bs + (wn * 64 + i * 16 + l15) * 64 + ca);
                #pragma unroll
                for (int mi = 0; mi < 2; mi++)
                    #pragma unroll
                    for (int ni = 0; ni < 4; ni++)
                        acc1[nh][mi][ni] = __builtin_amdgcn_mfma_f32_16x16x32_bf16(a[mi], bb[ni], acc1[nh][mi][ni], 0, 0, 0);
            }
        }
    }
    __syncthreads();
    #pragma unroll
    for (int nh = 0; nh < 2; nh++)
        #pragma unroll
        for (int ni = 0; ni < 4; ni++){
            float bv = b1f[nh * 128 + wn * 64 + ni * 16 + l15];
            int kcol = ni * 16 + l15;
            int chunk = nh * 2 + wn;
            #pragma unroll
            for (int mi = 0; mi < 2; mi++)
                #pragma unroll
                for (int j = 0; j < 4; j++){
                    int row = wm * 32 + mi * 16 + hi * 4 + j;
                    float v = fmaxf(acc1[nh][mi][ni][j] + bv, 0.f);
                    mid[chunk * 4096 + row * 64 + (((kcol >> 3) ^ (row & 7)) * 8 + (kcol & 7))] = f2bf(v);
                }
        }

    // ---- FFN2 ----
    f32x4 acc2[2][4];
    #pragma unroll
    for (int mi = 0; mi < 2; mi++)
        #pragma unroll
        for (int ni = 0; ni < 4; ni++)
            acc2[mi][ni] = (f32x4){0.f, 0.f, 0.f, 0.f};

    for (int kt = 0; kt < 4; kt++){
        __syncthreads();
        #pragma unroll
        for (int p = 0; p < 4; p++){
            int s = p * 4 + w;
            int row = s * 8 + lr;
            async16(W2t + (size_t)row * 256 + kt * 64 + swz, Bs + s * 512);
        }
        asm volatile("s_waitcnt vmcnt(0)" ::: "memory");
        __syncthreads();
        #pragma unroll
        for (int ks = 0; ks < 2; ks++){
            int ca = ((ks * 4 + hi) ^ (l15 & 7)) * 8;
            bf16x8 a[2], bb[4];
            #pragma unroll
            for (int i = 0; i < 2; i++)
                a[i] = *(const bf16x8*)(mid + kt * 4096 + (wm * 32 + i * 16 + l15) * 64 + ca);
            #pragma unroll
            for (int i = 0; i < 4; i++)
                bb[i] = *(const bf16x8*)(Bs + (wn * 64 + i * 16 + l15) * 64 + ca);
            #pragma unroll
            for (int mi = 0; mi < 2; mi++)
                #pragma unroll
                for (int ni = 0; ni < 4; ni++)
                    acc2[mi][ni] = __builtin_amdgcn_mfma_f32_16x16x32_bf16(a[mi], bb[ni], acc2[mi][ni], 0, 0, 0);
        }
    }

    // ---- LN2 (resid = h1 from LDS) ----
    float gc2[4], bc2[4], bv2[4];
    #pragma unroll
    for (int ni = 0; ni < 4; ni++){
        int col = wn * 64 + ni * 16 + l15;
        gc2[ni] = g2[col]; bc2[ni] = b2v[col]; bv2[ni] = b2f[col];
    }
    __syncthreads();
    #pragma unroll
    for (int mi = 0; mi < 2; mi++)
        #pragma unroll
        for (int j = 0; j < 4; j++){
            int row = wm * 32 + mi * 16 + hi * 4 + j;
            float s = 0.f, ss = 0.f;
            #pragma unroll
            for (int ni = 0; ni < 4; ni++){
                int kcol = ni * 16 + l15;
                float h1v = bf2f(h1c[wn * 4096 + row * 64 + (((kcol >> 3) ^ (row & 7)) * 8 + (kcol & 7))]);
                float x = acc2[mi][ni][j] + bv2[ni] + h1v;
                acc2[mi][ni][j] = x;
                s += x; ss += x * x;
            }
            #pragma unroll
            for (int d = 1; d < 16; d <<= 1){
                s  += __shfl_xor(s, d);
                ss += __shfl_xor(ss, d);
            }
            if (l15 == 0){ ps[wn][row] = s; pss[wn][row] = ss; }
        }
    __syncthreads();

    #pragma unroll
    for (int mi = 0; mi < 2; mi++)
        #pragma unroll
        for (int j = 0; j < 4; j++){
            int row = wm * 32 + mi * 16 + hi * 4 + j;
            int gr = m0 + row;
            if (gr >= M) continue;
            float s = ps[0][row] + ps[1][row];
            float ss = pss[0][row] + pss[1][row];
            float mean = s * (1.f / 128.f);
            float var = ss * (1.f / 128.f) - mean * mean;
            float r = rsqrtf(var + 1e-5f);
            #pragma unroll
            for (int ni = 0; ni < 4; ni++){
                int col = wn * 64 + ni * 16 + l15;
                float o = (acc2[mi][ni][j] - mean) * r * gc2[ni] + bc2[ni];
                if (out_f) out_f[(size_t)gr * 128 + col] = o;
                else {
                    u16 ob = f2bf(o);
                    out_bf[(size_t)gr * 128 + col] = ob;
                    if (Qb){   // keep h2 in LDS (h1c reuse, values retired)
                        int kcol = ni * 16 + l15;
                        h1c[wn * 4096 + row * 64 + (((kcol >> 3) ^ (row & 7)) * 8 + (kcol & 7))] = ob;
                    }
                }
            }
        }

    // ---- optional: next-layer QKV projection from LDS h2 ----
    if (!Qb) return;
    __syncthreads();   // h2c visible to all; mid free for Cs
    for (int nc = 0; nc < 6; nc++){
        __syncthreads();   // Bs / Cs reuse guard
        #pragma unroll
        for (int kh = 0; kh < 2; kh++)
            #pragma unroll
            for (int p = 0; p < 2; p++){
                int s = p * 4 + w;               // slice 0..7
                int row = s * 8 + lr;            // 0..63
                async16(WtQn + (size_t)(nc * 64 + row) * 128 + kh * 64 + swz,
                        Bs + kh * 4096 + s * 512);
            }
        asm volatile("s_waitcnt vmcnt(0)" ::: "memory");
        __syncthreads();
        f32x4 aq[2][2];
        #pragma unroll
        for (int mi = 0; mi < 2; mi++)
            #pragma unroll
            for (int ni = 0; ni < 2; ni++)
                aq[mi][ni] = (f32x4){0.f, 0.f, 0.f, 0.f};
        #pragma unroll
        for (int kh = 0; kh < 2; kh++)
            #pragma unroll
            for (int ks = 0; ks < 2; ks++){
                int ca = ((ks * 4 + hi) ^ (l15 & 7)) * 8;
                bf16x8 a[2], bb[2];
                #pragma unroll
                for (int i = 0; i < 2; i++){
                    a[i]  = *(const bf16x8*)(h1c + kh * 4096 + (wm * 32 + i * 16 + l15) * 64 + ca);
                    bb[i] = *(const bf16x8*)(Bs  + kh * 4096 + (wn * 32 + i * 16 + l15) * 64 + ca);
                }
                #pragma unroll
                for (int mi = 0; mi < 2; mi++)
                    #pragma unroll
                    for (int ni = 0; ni < 2; ni++)
                        aq[mi][ni] = __builtin_amdgcn_mfma_f32_16x16x32_bf16(a[mi], bb[ni], aq[mi][ni], 0, 0, 0);
            }
        // bias + bf16 into Cs [64][68]
        #pragma unroll
        for (int mi = 0; mi < 2; mi++)
            #pragma unroll
            for (int ni = 0; ni < 2; ni++){
                int col = wn * 32 + ni * 16 + l15;
                float bval = bQn[nc * 64 + col];
                #pragma unroll
                for (int j = 0; j < 4; j++){
                    int row = wm * 32 + mi * 16 + hi * 4 + j;
                    Cs[row * 68 + col] = f2bf(aq[mi][ni][j] + bval);
                }
            }
        __syncthreads();
        // coalesced store: 8 threads x 16B per row, 32 rows per pass
        int srow = tid >> 3, scol = (tid & 7) * 8;
        if (nc < 4){
            u16* Tb = (nc < 2) ? Qb : Kb;
            int cbase = (nc & 1) * 64;
            #pragma unroll
            for (int pass = 0; pass < 2; pass++){
                int row = pass * 32 + srow;
                int gr = m0 + row;
                if (gr < M){
                    uint4 v = *(const uint4*)(&Cs[row * 68 + scol]);
                    *(uint4*)(Tb + (size_t)gr * 128 + cbase + scol) = v;
                }
            }
        } else {
            int cbase = (nc & 1) * 64;
            #pragma unroll
            for (int pass = 0; pass < 2; pass++){
                int row = pass * 32 + srow;
                int gr = m0 + row;
                if (gr < M){
                    uint4 v = *(const uint4*)(&Cs[row * 68 + scol]);
                    float f0 = bf2f((u16)(v.x & 0xffff)), f1 = bf2f((u16)(v.x >> 16));
                    float f2 = bf2f((u16)(v.y & 0xffff)), f3 = bf2f((u16)(v.y >> 16));
                    float f4 = bf2f((u16)(v.z & 0xffff)), f5 = bf2f((u16)(v.z >> 16));
                    float f6 = bf2f((u16)(v.w & 0xffff)), f7 = bf2f((u16)(v.w >> 16));
                    unsigned int w0 = __builtin_amdgcn_cvt_pk_fp8_f32(f0, f1, 0u, false);
                    w0 = __builtin_amdgcn_cvt_pk_fp8_f32(f2, f3, w0, true);
                    unsigned int w1 = __builtin_amdgcn_cvt_pk_fp8_f32(f4, f5, 0u, false);
                    w1 = __builtin_amdgcn_cvt_pk_fp8_f32(f6, f7, w1, true);
                    *(uint2*)(Vb + (size_t)gr * 128 + cbase + scol) = make_uint2(w0, w1);
                }
            }
        }
    }
}

// ---------------- edge attention: bf16 K (8B) + fp8 V (4B) per edge per lane ----------------
__global__ __launch_bounds__(256) void edge_attn_kernel(const u16* __restrict__ Qb,
                                                        const u16* __restrict__ Kb,
                                                        const unsigned char* __restrict__ Vb,
                                                        const int* __restrict__ srcs,
                                                        const int* __restrict__ offs,
                                                        u16* __restrict__ att){
    int n = blockIdx.x * 4 + (threadIdx.x >> 6);
    if (n >= NN) return;
    int lane = threadIdx.x & 63;
    int laneh = lane & 31;
    int half = lane >> 5;

    float q0, q1, q2, q3;
    {
        uint2 qv = *(const uint2*)(Qb + (size_t)n * 128 + 4 * laneh);
        q0 = bf2f((u16)(qv.x & 0xffff)); q1 = bf2f((u16)(qv.x >> 16));
        q2 = bf2f((u16)(qv.y & 0xffff)); q3 = bf2f((u16)(qv.y >> 16));
    }
    const u16* kbase = Kb + 4 * laneh;
    const unsigned char* vbase = Vb + 4 * laneh;

    float w0 = 0.f, w1 = 0.f, w2 = 0.f, w3 = 0.f, z = 0.f;
    const float CS = 0.25f * 1.44269504f;

    auto proc = [&](uint2 kk, unsigned int vv, float gate){
        float k0 = bf2f((u16)(kk.x & 0xffff)), k1 = bf2f((u16)(kk.x >> 16));
        float k2 = bf2f((u16)(kk.y & 0xffff)), k3 = bf2f((u16)(kk.y >> 16));
        float p = q0 * k0 + q1 * k1 + q2 * k2 + q3 * k3;
        p += __shfl_xor(p, 1);
        p += __shfl_xor(p, 2);
        p = __builtin_amdgcn_fmed3f(p, -20.f, 20.f);
        float sc = __builtin_amdgcn_exp2f(p * CS) * gate;
        f32x2 vl = __builtin_amdgcn_cvt_pk_f32_fp8(vv, false);
        f32x2 vh = __builtin_amdgcn_cvt_pk_f32_fp8(vv, true);
        w0 += sc * vl[0]; w1 += sc * vl[1]; w2 += sc * vh[0]; w3 += sc * vh[1];
        z += sc;
    };

    int e0 = offs[n], e1 = offs[n + 1];
    int i = e0;
    for (; i + 15 < e1; i += 16){
        int s[8];
        #pragma unroll
        for (int u = 0; u < 8; u++) s[u] = srcs[i + 2 * u + half];
        uint2 kk[8];
        unsigned int vv[8];
        #pragma unroll
        for (int u = 0; u < 8; u++){
            kk[u] = *(const uint2*)(kbase + (size_t)s[u] * 128);
            vv[u] = *(const unsigned int*)(vbase + (size_t)s[u] * 128);
        }
        #pragma unroll
        for (int u = 0; u < 8; u++) proc(kk[u], vv[u], 1.f);
    }
    for (; i + 1 < e1; i += 2){
        int s = srcs[i + half];
        proc(*(const uint2*)(kbase + (size_t)s * 128),
             *(const unsigned int*)(vbase + (size_t)s * 128), 1.f);
    }
    if (i < e1){
        int s = srcs[i];
        proc(*(const uint2*)(kbase + (size_t)s * 128),
             *(const unsigned int*)(vbase + (size_t)s * 128), half ? 0.f : 1.f);
    }

    w0 += __shfl_xor(w0, 32); w1 += __shfl_xor(w1, 32);
    w2 += __shfl_xor(w2, 32); w3 += __shfl_xor(w3, 32);
    z  += __shfl_xor(z, 32);

    if (!half){
        float inv = 1.f / (z + 1e-6f);
        unsigned int oA = (unsigned int)f2bf(w0 * inv) | ((unsigned int)f2bf(w1 * inv) << 16);
        unsigned int oB = (unsigned int)f2bf(w2 * inv) | ((unsigned int)f2bf(w3 * inv) << 16);
        *(uint2*)(att + (size_t)n * DD + 4 * laneh) = make_uint2(oA, oB);
    }
}

// ---------------- host orchestration ----------------
extern "C" void kernel_launch(void* const* d_in, const int* in_sizes, int n_in,
                              void* d_out, int out_size, void* d_ws, size_t ws_size,
                              hipStream_t stream){
    const float* h_in = (const float*)d_in[0];
    const int* src  = (const int*)d_in[1];
    const int* dst  = (const int*)d_in[2];
    const float* Wq = (const float*)d_in[3];
    const float* bq = (const float*)d_in[4];
    const float* Wk = (const float*)d_in[5];
    const float* bk = (const float*)d_in[6];
    const float* Wv = (const float*)d_in[7];
    const float* bv = (const float*)d_in[8];
    const float* Wo = (const float*)d_in[9];
    const float* bo = (const float*)d_in[10];
    const float* W1 = (const float*)d_in[11];
    const float* b1 = (const float*)d_in[12];
    const float* W2 = (const float*)d_in[13];
    const float* b2 = (const float*)d_in[14];
    const float* ln1_g = (const float*)d_in[15];
    const float* ln1_b = (const float*)d_in[16];
    const float* ln2_g = (const float*)d_in[17];
    const float* ln2_b = (const float*)d_in[18];
    float* outp = (float*)d_out;

    char* ws = (char*)d_ws;
    auto alloc = [&](size_t bytes) -> char* {
        char* p = ws;
        ws += (bytes + 255) & ~(size_t)255;
        return p;
    };
    int* cnt   = (int*)alloc((size_t)NN * 4);
    int* offs  = (int*)alloc((size_t)(NN + 1) * 4);
    int* cur   = (int*)alloc((size_t)(NN + 1) * 4);
    int* srcs  = (int*)alloc((size_t)EE * 4);
    u16* WtQKV = (u16*)alloc((size_t)LL * 384 * 128 * 2);
    float* bQKV = (float*)alloc((size_t)LL * 384 * 4);
    u16* WtO   = (u16*)alloc((size_t)LL * 128 * 128 * 2);
    u16* WtF1  = (u16*)alloc((size_t)LL * 256 * 128 * 2);
    u16* WtF2  = (u16*)alloc((size_t)LL * 128 * 256 * 2);
    u16* hb    = (u16*)alloc((size_t)NN * DD * 2);
    u16* Qb    = (u16*)alloc((size_t)NN * 128 * 2);
    u16* Kb    = (u16*)alloc((size_t)NN * 128 * 2);
    unsigned char* Vb = (unsigned char*)alloc((size_t)NN * 128);
    u16* att   = (u16*)alloc((size_t)NN * DD * 2);
    u16* hmid  = (u16*)alloc((size_t)NN * DD * 2);

    hipMemsetAsync(cnt, 0, (size_t)NN * 4, stream);
    prep_kernel<<<PREP_BLOCKS, 256, 0, stream>>>(dst, cnt, h_in, hb,
                                                 Wq, Wk, Wv, bq, bk, bv, WtQKV, bQKV,
                                                 Wo, W1, W2, WtO, WtF1, WtF2);
    scan_kernel<<<1, 1024, 0, stream>>>(cnt, offs, cur);
    fill_kernel<<<8 * FILL_SUB, 256, 0, stream>>>(src, dst, cur, srcs);

    const int MB = (NN + BM - 1) / BM;     // 391
    const int MB64 = (NN + 63) / 64;       // 782

    // layer 0
    gemm_qkv<<<dim3(MB, 3), 256, 0, stream>>>(hb, WtQKV, bQKV, Qb, Kb, Vb, NN);
    edge_attn_kernel<<<NN / 4, 256, 0, stream>>>(Qb, Kb, Vb, srcs, offs, att);
    tail_kernel<<<MB64, 256, 0, stream>>>(att, WtO, bo, hb, ln1_g, ln1_b,
                                          WtF1, b1, WtF2, b2, ln2_g, ln2_b,
                                          hmid, nullptr,
                                          WtQKV + (size_t)384 * 128, bQKV + 384,   // next-layer QKV
                                          Qb, Kb, Vb, NN);
    // layer 1
    edge_attn_kernel<<<NN / 4, 256, 0, stream>>>(Qb, Kb, Vb, srcs, offs, att);
    tail_kernel<<<MB64, 256, 0, stream>>>(att, WtO + (size_t)128 * 128, bo + 128,
                                          hmid, ln1_g + 128, ln1_b + 128,
                                          WtF1 + (size_t)256 * 128, b1 + 256,
                                          WtF2 + (size_t)128 * 256, b2 + 128,
                                          ln2_g + 128, ln2_b + 128,
                                          nullptr, outp,
                                          nullptr, nullptr, nullptr, nullptr, nullptr, NN);
}

// Round 16
// 458.284 us; speedup vs baseline: 1.1668x; 1.1668x over previous
//
#include <hip/hip_runtime.h>

#define NN 50000
#define DD 128
#define HH 8
#define EE 1600000
#define LL 2

typedef unsigned short u16;
typedef __attribute__((ext_vector_type(8))) __bf16 bf16x8;
typedef __attribute__((ext_vector_type(4))) float f32x4;
typedef __attribute__((ext_vector_type(2))) float f32x2;

__device__ __forceinline__ float bf2f(u16 u){
    return __uint_as_float(((unsigned int)u) << 16);
}
__device__ __forceinline__ u16 f2bf(float f){
    unsigned int x = __float_as_uint(f);
    x = x + 0x7fff + ((x >> 16) & 1);   // round-to-nearest-even
    return (u16)(x >> 16);
}

// async global->LDS, 16B per lane, linear dest (wave base + lane*16)
__device__ __forceinline__ void async16(const u16* g, u16* l){
    __builtin_amdgcn_global_load_lds(
        (const __attribute__((address_space(1))) unsigned int*)(const void*)g,
        (__attribute__((address_space(3))) unsigned int*)(void*)l, 16, 0, 0);
}

// ---------------- mega-prep: count | f2b4 | qkvpack | wprep in ONE launch ----------------
#define FILL_SUB 128
#define PREP_BLOCKS (1024 + 6250 + 384 + 768)

__global__ __launch_bounds__(256) void prep_kernel(
        const int* __restrict__ dst, int* __restrict__ cnt,
        const float* __restrict__ h_in, u16* __restrict__ hb,
        const float* __restrict__ Wq, const float* __restrict__ Wk, const float* __restrict__ Wv,
        const float* __restrict__ bq, const float* __restrict__ bk, const float* __restrict__ bv,
        u16* __restrict__ WtQKV, float* __restrict__ bQKV,
        const float* __restrict__ Wo, const float* __restrict__ W1, const float* __restrict__ W2,
        u16* __restrict__ WtO, u16* __restrict__ WtF1, u16* __restrict__ WtF2){
    int b = blockIdx.x;
    if (b < 1024){
        int slice = b & 7;
        int sub = b >> 3;
        int lo = slice * (NN / 8), hi = lo + (NN / 8);
        for (int e = sub * 256 + threadIdx.x; e < EE; e += FILL_SUB * 256){
            int d = dst[e];
            if (d >= lo && d < hi) atomicAdd(&cnt[d], 1);
        }
        return;
    }
    b -= 1024;
    if (b < 6250){
        int i = b * 256 + threadIdx.x;
        if (i < NN * DD / 4){
            float4 v = ((const float4*)h_in)[i];
            ushort4 o;
            o.x = f2bf(v.x); o.y = f2bf(v.y); o.z = f2bf(v.z); o.w = f2bf(v.w);
            ((ushort4*)hb)[i] = o;
        }
        return;
    }
    b -= 6250;
    if (b < 384){
        int l = b / 192;
        int idx = (b % 192) * 256 + threadIdx.x;
        if (idx < 384 * 128){
            int n = idx >> 7, k = idx & 127;
            const float* W = (n < 128) ? Wq : (n < 256) ? Wk : Wv;
            int nc = n & 127;
            WtQKV[(size_t)l * 384 * 128 + idx] = f2bf(W[(size_t)l * 128 * 128 + k * 128 + nc]);
            if (k == 0){
                const float* bb = (n < 128) ? bq : (n < 256) ? bk : bv;
                bQKV[l * 384 + n] = bb[l * 128 + nc];
            }
        }
        return;
    }
    b -= 384;
    {
        int which = b / 256;
        int rem = b % 256;
        int l = rem / 128;
        int idx = (rem % 128) * 256 + threadIdx.x;
        const float* in; u16* out; int R, C;
        if (which == 0){ in = Wo; out = WtO; R = 128; C = 128; }
        else if (which == 1){ in = W1; out = WtF1; R = 128; C = 256; }
        else { in = W2; out = WtF2; R = 256; C = 128; }
        int total = R * C;
        if (idx < total){
            size_t mat = (size_t)l * total;
            int r = idx / C, c = idx % C;
            out[mat + (size_t)c * R + r] = f2bf(in[mat + idx]);
        }
    }
}

// ---------------- CSR scan + fill ----------------
__global__ __launch_bounds__(1024) void scan_kernel(const int* __restrict__ cnt,
                                                    int* __restrict__ offs, int* __restrict__ cur){
    __shared__ int wsum[16];
    __shared__ int carry_s;
    __shared__ int ctot_s;
    int t = threadIdx.x, lane = t & 63, w = t >> 6;
    if (t == 0){ offs[0] = 0; cur[0] = 0; carry_s = 0; }
    __syncthreads();
    const int N4 = NN / 4;
    for (int base = 0; base < N4; base += 1024){
        int i4 = base + t;
        int4 x = (i4 < N4) ? ((const int4*)cnt)[i4] : make_int4(0, 0, 0, 0);
        int s1 = x.x, s2 = s1 + x.y, s3 = s2 + x.z, s4 = s3 + x.w;
        int v = s4;
        #pragma unroll
        for (int d = 1; d < 64; d <<= 1){ int u = __shfl_up(v, d); if (lane >= d) v += u; }
        if (lane == 63) wsum[w] = v;
        __syncthreads();
        if (t < 16){
            int sv = wsum[t];
            int iv = sv;
            #pragma unroll
            for (int d = 1; d < 16; d <<= 1){ int u = __shfl_up(iv, d); if (t >= d) iv += u; }
            wsum[t] = iv - sv;
            if (t == 15) ctot_s = iv;
        }
        __syncthreads();
        int excl = carry_s + wsum[w] + (v - s4);
        if (i4 < N4){
            int o = 4 * i4;
            offs[o + 1] = excl + s1;  cur[o + 1] = excl + s1;
            offs[o + 2] = excl + s2;  cur[o + 2] = excl + s2;
            offs[o + 3] = excl + s3;  cur[o + 3] = excl + s3;
            offs[o + 4] = excl + s4;  cur[o + 4] = excl + s4;
        }
        __syncthreads();
        if (t == 0) carry_s += ctot_s;
        __syncthreads();
    }
}

__global__ __launch_bounds__(256) void fill_kernel(const int* __restrict__ src, const int* __restrict__ dst,
                                                   int* __restrict__ cur, int* __restrict__ srcs){
    int slice = blockIdx.x & 7;
    int sub = blockIdx.x >> 3;
    int lo = slice * (NN / 8), hi = lo + (NN / 8);
    for (int e = sub * 256 + threadIdx.x; e < EE; e += FILL_SUB * 256){
        int d = dst[e];
        if (d >= lo && d < hi){
            int p = atomicAdd(&cur[d], 1);
            srcs[p] = src[e];
        }
    }
}

// ================= GEMM core helpers (global_load_lds + XOR swizzle) ==========
#define BM 128
#define LDC 136

__device__ __forceinline__ void stage_tile(const u16* __restrict__ A, const u16* __restrict__ Wt,
                                           u16* As, u16* Bs, int M, int K, int m0, int n0, int k0,
                                           int w, int lane){
    int lr = lane >> 3;
    int swz = ((lane & 7) ^ lr) * 8;
    #pragma unroll
    for (int p = 0; p < 4; p++){
        int s = p * 4 + w;
        int ga = m0 + s * 8 + lr;
        if (ga >= M) ga = M - 1;
        async16(A + (size_t)ga * K + k0 + swz, As + s * 512);
        async16(Wt + (size_t)(n0 + s * 8 + lr) * K + k0 + swz, Bs + s * 512);
    }
}

__device__ __forceinline__ void mfma_tiles(const u16* As, const u16* Bs, f32x4 (&acc)[4][4],
                                           int wm, int wn, int l15, int hi){
    #pragma unroll
    for (int ks = 0; ks < 2; ks++){
        bf16x8 a[4], b[4];
        int ca = ((ks * 4 + hi) ^ (l15 & 7)) * 8;
        #pragma unroll
        for (int i = 0; i < 4; i++){
            a[i] = *(const bf16x8*)(As + (wm * 64 + i * 16 + l15) * 64 + ca);
            b[i] = *(const bf16x8*)(Bs + (wn * 64 + i * 16 + l15) * 64 + ca);
        }
        #pragma unroll
        for (int mi = 0; mi < 4; mi++)
            #pragma unroll
            for (int ni = 0; ni < 4; ni++)
                acc[mi][ni] = __builtin_amdgcn_mfma_f32_16x16x32_bf16(a[mi], b[ni], acc[mi][ni], 0, 0, 0);
    }
}

#define GEMM_LOOP(K)                                                          \
    for (int k0 = 0; k0 < (K); k0 += 64){                                     \
        __syncthreads();                                                      \
        stage_tile(A, Wt, As, Bs, M, (K), m0, n0, k0, w, lane);               \
        asm volatile("s_waitcnt vmcnt(0)" ::: "memory");                      \
        __syncthreads();                                                      \
        mfma_tiles(As, Bs, acc, wm, wn, l15, hi);                             \
    }

// QKV GEMM: n0=0 -> Qb bf16, n0=128 -> Kb bf16, n0=256 -> Vb fp8 e4m3
__global__ __launch_bounds__(256) void gemm_qkv(const u16* __restrict__ A, const u16* __restrict__ Wt,
                                                const float* __restrict__ bias,
                                                u16* __restrict__ Qb, u16* __restrict__ Kb,
                                                unsigned char* __restrict__ Vb, int M){
    __shared__ __align__(16) char smem[128 * LDC * 2];
    u16* As = (u16*)smem;
    u16* Bs = As + 8192;
    u16* Cs = (u16*)smem;

    int tid = threadIdx.x;
    int m0 = blockIdx.x * BM, n0 = blockIdx.y * 128;
    int lane = tid & 63, w = tid >> 6;
    int wm = w >> 1, wn = w & 1;
    int l15 = lane & 15, hi = lane >> 4;

    f32x4 acc[4][4];
    #pragma unroll
    for (int mi = 0; mi < 4; mi++)
        #pragma unroll
        for (int ni = 0; ni < 4; ni++)
            acc[mi][ni] = (f32x4){0.f, 0.f, 0.f, 0.f};

    GEMM_LOOP(128)

    __syncthreads();
    #pragma unroll
    for (int mi = 0; mi < 4; mi++)
        #pragma unroll
        for (int ni = 0; ni < 4; ni++){
            int col = wn * 64 + ni * 16 + l15;
            float bval = bias[n0 + col];
            #pragma unroll
            for (int j = 0; j < 4; j++){
                int rl = wm * 64 + mi * 16 + hi * 4 + j;
                Cs[rl * LDC + col] = f2bf(acc[mi][ni][j] + bval);
            }
        }
    __syncthreads();
    int qrow = tid >> 4, quad = tid & 15;
    if (n0 < 256){
        u16* Tb = (n0 == 0) ? Qb : Kb;
        #pragma unroll
        for (int p = 0; p < 8; p++){
            int rl = p * 16 + qrow;
            int gr = m0 + rl;
            if (gr < M){
                uint4 v = *(const uint4*)(&Cs[rl * LDC + quad * 8]);
                *(uint4*)(Tb + (size_t)gr * 128 + quad * 8) = v;
            }
        }
    } else {
        #pragma unroll
        for (int p = 0; p < 8; p++){
            int rl = p * 16 + qrow;
            int gr = m0 + rl;
            if (gr < M){
                uint4 v = *(const uint4*)(&Cs[rl * LDC + quad * 8]);
                float f0 = bf2f((u16)(v.x & 0xffff)), f1 = bf2f((u16)(v.x >> 16));
                float f2 = bf2f((u16)(v.y & 0xffff)), f3 = bf2f((u16)(v.y >> 16));
                float f4 = bf2f((u16)(v.z & 0xffff)), f5 = bf2f((u16)(v.z >> 16));
                float f6 = bf2f((u16)(v.w & 0xffff)), f7 = bf2f((u16)(v.w >> 16));
                unsigned int w0 = __builtin_amdgcn_cvt_pk_fp8_f32(f0, f1, 0u, false);
                w0 = __builtin_amdgcn_cvt_pk_fp8_f32(f2, f3, w0, true);
                unsigned int w1 = __builtin_amdgcn_cvt_pk_fp8_f32(f4, f5, 0u, false);
                w1 = __builtin_amdgcn_cvt_pk_fp8_f32(f6, f7, w1, true);
                *(uint2*)(Vb + (size_t)gr * 128 + quad * 8) = make_uint2(w0, w1);
            }
        }
    }
}

// ================= layer tail: O-proj+LN1+FFN1+relu+FFN2+LN2, one 64-row tile =================
__global__ __launch_bounds__(256) void tail_kernel(const u16* __restrict__ att,
                                                   const u16* __restrict__ WtO, const float* __restrict__ bo,
                                                   const u16* __restrict__ resid,
                                                   const float* __restrict__ g1, const float* __restrict__ b1v,
                                                   const u16* __restrict__ W1t, const float* __restrict__ b1f,
                                                   const u16* __restrict__ W2t, const float* __restrict__ b2f,
                                                   const float* __restrict__ g2, const float* __restrict__ b2v,
                                                   u16* __restrict__ out_bf, float* __restrict__ out_f,
                                                   int M){
    __shared__ __align__(16) u16 h1c[8192];     // 16KB: 2 chunks [64][64] (swizzled)
    __shared__ __align__(16) u16 mid[16384];    // 32KB: 4 chunks [64][64] (swizzled)
    __shared__ __align__(16) u16 Bs[8192];      // 16KB B staging
    __shared__ float ps[2][64];
    __shared__ float pss[2][64];
    u16* AsO = mid;                             // O-proj A staging overlay (8KB)

    int tid = threadIdx.x, lane = tid & 63, w = tid >> 6;
    int l15 = lane & 15, hi = lane >> 4;
    int wm = w >> 1, wn = w & 1;
    int m0 = blockIdx.x * 64;
    int lr = lane >> 3;
    int swz = ((lane & 7) ^ lr) * 8;

    // ---- O-proj ----
    f32x4 acc0[2][4];
    #pragma unroll
    for (int mi = 0; mi < 2; mi++)
        #pragma unroll
        for (int ni = 0; ni < 4; ni++)
            acc0[mi][ni] = (f32x4){0.f, 0.f, 0.f, 0.f};

    for (int kh = 0; kh < 2; kh++){
        __syncthreads();
        #pragma unroll
        for (int p = 0; p < 2; p++){
            int s = p * 4 + w;
            int ga = m0 + s * 8 + lr;
            if (ga >= M) ga = M - 1;
            async16(att + (size_t)ga * 128 + kh * 64 + swz, AsO + s * 512);
        }
        #pragma unroll
        for (int p = 0; p < 4; p++){
            int s = p * 4 + w;
            int row = s * 8 + lr;
            async16(WtO + (size_t)row * 128 + kh * 64 + swz, Bs + s * 512);
        }
        asm volatile("s_waitcnt vmcnt(0)" ::: "memory");
        __syncthreads();
        #pragma unroll
        for (int ks = 0; ks < 2; ks++){
            int ca = ((ks * 4 + hi) ^ (l15 & 7)) * 8;
            bf16x8 a[2], bb[4];
            #pragma unroll
            for (int i = 0; i < 2; i++)
                a[i] = *(const bf16x8*)(AsO + (wm * 32 + i * 16 + l15) * 64 + ca);
            #pragma unroll
            for (int i = 0; i < 4; i++)
                bb[i] = *(const bf16x8*)(Bs + (wn * 64 + i * 16 + l15) * 64 + ca);
            #pragma unroll
            for (int mi = 0; mi < 2; mi++)
                #pragma unroll
                for (int ni = 0; ni < 4; ni++)
                    acc0[mi][ni] = __builtin_amdgcn_mfma_f32_16x16x32_bf16(a[mi], bb[ni], acc0[mi][ni], 0, 0, 0);
        }
    }

    // ---- LN1 -> h1c ----
    {
        float gc[4], bc[4], bv[4];
        #pragma unroll
        for (int ni = 0; ni < 4; ni++){
            int col = wn * 64 + ni * 16 + l15;
            gc[ni] = g1[col]; bc[ni] = b1v[col]; bv[ni] = bo[col];
        }
        #pragma unroll
        for (int mi = 0; mi < 2; mi++)
            #pragma unroll
            for (int j = 0; j < 4; j++){
                int row = wm * 32 + mi * 16 + hi * 4 + j;
                int gr = m0 + row;
                float s = 0.f, ss = 0.f;
                #pragma unroll
                for (int ni = 0; ni < 4; ni++){
                    int col = wn * 64 + ni * 16 + l15;
                    float x = acc0[mi][ni][j] + bv[ni];
                    if (gr < M) x += bf2f(resid[(size_t)gr * 128 + col]);
                    acc0[mi][ni][j] = x;
                    s += x; ss += x * x;
                }
                #pragma unroll
                for (int d = 1; d < 16; d <<= 1){
                    s  += __shfl_xor(s, d);
                    ss += __shfl_xor(ss, d);
                }
                if (l15 == 0){ ps[wn][row] = s; pss[wn][row] = ss; }
            }
        __syncthreads();
        #pragma unroll
        for (int mi = 0; mi < 2; mi++)
            #pragma unroll
            for (int j = 0; j < 4; j++){
                int row = wm * 32 + mi * 16 + hi * 4 + j;
                float s = ps[0][row] + ps[1][row];
                float ss = pss[0][row] + pss[1][row];
                float mean = s * (1.f / 128.f);
                float var = ss * (1.f / 128.f) - mean * mean;
                float r = rsqrtf(var + 1e-5f);
                #pragma unroll
                for (int ni = 0; ni < 4; ni++){
                    int kcol = ni * 16 + l15;
                    float o = (acc0[mi][ni][j] - mean) * r * gc[ni] + bc[ni];
                    h1c[wn * 4096 + row * 64 + (((kcol >> 3) ^ (row & 7)) * 8 + (kcol & 7))] = f2bf(o);
                }
            }
    }

    // ---- FFN1 ----
    f32x4 acc1[2][2][4];
    #pragma unroll
    for (int nh = 0; nh < 2; nh++)
        #pragma unroll
        for (int mi = 0; mi < 2; mi++)
            #pragma unroll
            for (int ni = 0; ni < 4; ni++)
                acc1[nh][mi][ni] = (f32x4){0.f, 0.f, 0.f, 0.f};

    for (int nh = 0; nh < 2; nh++){
        for (int kh = 0; kh < 2; kh++){
            __syncthreads();
            #pragma unroll
            for (int p = 0; p < 4; p++){
                int s = p * 4 + w;
                int row = s * 8 + lr;
                async16(W1t + (size_t)(nh * 128 + row) * 128 + kh * 64 + swz, Bs + s * 512);
            }
            asm volatile("s_waitcnt vmcnt(0)" ::: "memory");
            __syncthreads();
            #pragma unroll
            for (int ks = 0; ks < 2; ks++){
                int ca = ((ks * 4 + hi) ^ (l15 & 7)) * 8;
                bf16x8 a[2], bb[4];
                #pragma unroll
                for (int i = 0; i < 2; i++)
                    a[i] = *(const bf16x8*)(h1c + kh * 4096 + (wm * 32 + i * 16 + l15) * 64 + ca);
                #pragma unroll
                for (int i = 0; i < 4; i++)
                    bb[i] = *(const bf16x8*)(Bs + (wn * 64 + i * 16 + l15) * 64 + ca);
                #pragma unroll
                for (int mi = 0; mi < 2; mi++)
                    #pragma unroll
                    for (int ni = 0; ni < 4; ni++)
                        acc1[nh][mi][ni] = __builtin_amdgcn_mfma_f32_16x16x32_bf16(a[mi], bb[ni], acc1[nh][mi][ni], 0, 0, 0);
            }
        }
    }
    __syncthreads();
    #pragma unroll
    for (int nh = 0; nh < 2; nh++)
        #pragma unroll
        for (int ni = 0; ni < 4; ni++){
            float bv = b1f[nh * 128 + wn * 64 + ni * 16 + l15];
            int kcol = ni * 16 + l15;
            int chunk = nh * 2 + wn;
            #pragma unroll
            for (int mi = 0; mi < 2; mi++)
                #pragma unroll
                for (int j = 0; j < 4; j++){
                    int row = wm * 32 + mi * 16 + hi * 4 + j;
                    float v = fmaxf(acc1[nh][mi][ni][j] + bv, 0.f);
                    mid[chunk * 4096 + row * 64 + (((kcol >> 3) ^ (row & 7)) * 8 + (kcol & 7))] = f2bf(v);
                }
        }

    // ---- FFN2 ----
    f32x4 acc2[2][4];
    #pragma unroll
    for (int mi = 0; mi < 2; mi++)
        #pragma unroll
        for (int ni = 0; ni < 4; ni++)
            acc2[mi][ni] = (f32x4){0.f, 0.f, 0.f, 0.f};

    for (int kt = 0; kt < 4; kt++){
        __syncthreads();
        #pragma unroll
        for (int p = 0; p < 4; p++){
            int s = p * 4 + w;
            int row = s * 8 + lr;
            async16(W2t + (size_t)row * 256 + kt * 64 + swz, Bs + s * 512);
        }
        asm volatile("s_waitcnt vmcnt(0)" ::: "memory");
        __syncthreads();
        #pragma unroll
        for (int ks = 0; ks < 2; ks++){
            int ca = ((ks * 4 + hi) ^ (l15 & 7)) * 8;
            bf16x8 a[2], bb[4];
            #pragma unroll
            for (int i = 0; i < 2; i++)
                a[i] = *(const bf16x8*)(mid + kt * 4096 + (wm * 32 + i * 16 + l15) * 64 + ca);
            #pragma unroll
            for (int i = 0; i < 4; i++)
                bb[i] = *(const bf16x8*)(Bs + (wn * 64 + i * 16 + l15) * 64 + ca);
            #pragma unroll
            for (int mi = 0; mi < 2; mi++)
                #pragma unroll
                for (int ni = 0; ni < 4; ni++)
                    acc2[mi][ni] = __builtin_amdgcn_mfma_f32_16x16x32_bf16(a[mi], bb[ni], acc2[mi][ni], 0, 0, 0);
        }
    }

    // ---- LN2 (resid = h1 from LDS) ----
    float gc2[4], bc2[4], bv2[4];
    #pragma unroll
    for (int ni = 0; ni < 4; ni++){
        int col = wn * 64 + ni * 16 + l15;
        gc2[ni] = g2[col]; bc2[ni] = b2v[col]; bv2[ni] = b2f[col];
    }
    __syncthreads();
    #pragma unroll
    for (int mi = 0; mi < 2; mi++)
        #pragma unroll
        for (int j = 0; j < 4; j++){
            int row = wm * 32 + mi * 16 + hi * 4 + j;
            float s = 0.f, ss = 0.f;
            #pragma unroll
            for (int ni = 0; ni < 4; ni++){
                int kcol = ni * 16 + l15;
                float h1v = bf2f(h1c[wn * 4096 + row * 64 + (((kcol >> 3) ^ (row & 7)) * 8 + (kcol & 7))]);
                float x = acc2[mi][ni][j] + bv2[ni] + h1v;
                acc2[mi][ni][j] = x;
                s += x; ss += x * x;
            }
            #pragma unroll
            for (int d = 1; d < 16; d <<= 1){
                s  += __shfl_xor(s, d);
                ss += __shfl_xor(ss, d);
            }
            if (l15 == 0){ ps[wn][row] = s; pss[wn][row] = ss; }
        }
    __syncthreads();

    #pragma unroll
    for (int mi = 0; mi < 2; mi++)
        #pragma unroll
        for (int j = 0; j < 4; j++){
            int row = wm * 32 + mi * 16 + hi * 4 + j;
            int gr = m0 + row;
            if (gr >= M) continue;
            float s = ps[0][row] + ps[1][row];
            float ss = pss[0][row] + pss[1][row];
            float mean = s * (1.f / 128.f);
            float var = ss * (1.f / 128.f) - mean * mean;
            float r = rsqrtf(var + 1e-5f);
            #pragma unroll
            for (int ni = 0; ni < 4; ni++){
                int col = wn * 64 + ni * 16 + l15;
                float o = (acc2[mi][ni][j] - mean) * r * gc2[ni] + bc2[ni];
                if (out_f) out_f[(size_t)gr * 128 + col] = o;
                else       out_bf[(size_t)gr * 128 + col] = f2bf(o);
            }
        }
}

// ---------------- edge attention: bf16 K (8B) + fp8 V (4B) per edge per lane ----------------
__global__ __launch_bounds__(256) void edge_attn_kernel(const u16* __restrict__ Qb,
                                                        const u16* __restrict__ Kb,
                                                        const unsigned char* __restrict__ Vb,
                                                        const int* __restrict__ srcs,
                                                        const int* __restrict__ offs,
                                                        u16* __restrict__ att){
    int n = blockIdx.x * 4 + (threadIdx.x >> 6);
    if (n >= NN) return;
    int lane = threadIdx.x & 63;
    int laneh = lane & 31;
    int half = lane >> 5;

    float q0, q1, q2, q3;
    {
        uint2 qv = *(const uint2*)(Qb + (size_t)n * 128 + 4 * laneh);
        q0 = bf2f((u16)(qv.x & 0xffff)); q1 = bf2f((u16)(qv.x >> 16));
        q2 = bf2f((u16)(qv.y & 0xffff)); q3 = bf2f((u16)(qv.y >> 16));
    }
    const u16* kbase = Kb + 4 * laneh;
    const unsigned char* vbase = Vb + 4 * laneh;

    float w0 = 0.f, w1 = 0.f, w2 = 0.f, w3 = 0.f, z = 0.f;
    const float CS = 0.25f * 1.44269504f;

    auto proc = [&](uint2 kk, unsigned int vv, float gate){
        float k0 = bf2f((u16)(kk.x & 0xffff)), k1 = bf2f((u16)(kk.x >> 16));
        float k2 = bf2f((u16)(kk.y & 0xffff)), k3 = bf2f((u16)(kk.y >> 16));
        float p = q0 * k0 + q1 * k1 + q2 * k2 + q3 * k3;
        p += __shfl_xor(p, 1);
        p += __shfl_xor(p, 2);
        p = __builtin_amdgcn_fmed3f(p, -20.f, 20.f);
        float sc = __builtin_amdgcn_exp2f(p * CS) * gate;
        f32x2 vl = __builtin_amdgcn_cvt_pk_f32_fp8(vv, false);
        f32x2 vh = __builtin_amdgcn_cvt_pk_f32_fp8(vv, true);
        w0 += sc * vl[0]; w1 += sc * vl[1]; w2 += sc * vh[0]; w3 += sc * vh[1];
        z += sc;
    };

    int e0 = offs[n], e1 = offs[n + 1];
    int i = e0;
    for (; i + 15 < e1; i += 16){
        int s[8];
        #pragma unroll
        for (int u = 0; u < 8; u++) s[u] = srcs[i + 2 * u + half];
        uint2 kk[8];
        unsigned int vv[8];
        #pragma unroll
        for (int u = 0; u < 8; u++){
            kk[u] = *(const uint2*)(kbase + (size_t)s[u] * 128);
            vv[u] = *(const unsigned int*)(vbase + (size_t)s[u] * 128);
        }
        #pragma unroll
        for (int u = 0; u < 8; u++) proc(kk[u], vv[u], 1.f);
    }
    for (; i + 1 < e1; i += 2){
        int s = srcs[i + half];
        proc(*(const uint2*)(kbase + (size_t)s * 128),
             *(const unsigned int*)(vbase + (size_t)s * 128), 1.f);
    }
    if (i < e1){
        int s = srcs[i];
        proc(*(const uint2*)(kbase + (size_t)s * 128),
             *(const unsigned int*)(vbase + (size_t)s * 128), half ? 0.f : 1.f);
    }

    w0 += __shfl_xor(w0, 32); w1 += __shfl_xor(w1, 32);
    w2 += __shfl_xor(w2, 32); w3 += __shfl_xor(w3, 32);
    z  += __shfl_xor(z, 32);

    if (!half){
        float inv = 1.f / (z + 1e-6f);
        unsigned int oA = (unsigned int)f2bf(w0 * inv) | ((unsigned int)f2bf(w1 * inv) << 16);
        unsigned int oB = (unsigned int)f2bf(w2 * inv) | ((unsigned int)f2bf(w3 * inv) << 16);
        *(uint2*)(att + (size_t)n * DD + 4 * laneh) = make_uint2(oA, oB);
    }
}

// ---------------- host orchestration ----------------
extern "C" void kernel_launch(void* const* d_in, const int* in_sizes, int n_in,
                              void* d_out, int out_size, void* d_ws, size_t ws_size,
                              hipStream_t stream){
    const float* h_in = (const float*)d_in[0];
    const int* src  = (const int*)d_in[1];
    const int* dst  = (const int*)d_in[2];
    const float* Wq = (const float*)d_in[3];
    const float* bq = (const float*)d_in[4];
    const float* Wk = (const float*)d_in[5];
    const float* bk = (const float*)d_in[6];
    const float* Wv = (const float*)d_in[7];
    const float* bv = (const float*)d_in[8];
    const float* Wo = (const float*)d_in[9];
    const float* bo = (const float*)d_in[10];
    const float* W1 = (const float*)d_in[11];
    const float* b1 = (const float*)d_in[12];
    const float* W2 = (const float*)d_in[13];
    const float* b2 = (const float*)d_in[14];
    const float* ln1_g = (const float*)d_in[15];
    const float* ln1_b = (const float*)d_in[16];
    const float* ln2_g = (const float*)d_in[17];
    const float* ln2_b = (const float*)d_in[18];
    float* outp = (float*)d_out;

    char* ws = (char*)d_ws;
    auto alloc = [&](size_t bytes) -> char* {
        char* p = ws;
        ws += (bytes + 255) & ~(size_t)255;
        return p;
    };
    int* cnt   = (int*)alloc((size_t)NN * 4);
    int* offs  = (int*)alloc((size_t)(NN + 1) * 4);
    int* cur   = (int*)alloc((size_t)(NN + 1) * 4);
    int* srcs  = (int*)alloc((size_t)EE * 4);
    u16* WtQKV = (u16*)alloc((size_t)LL * 384 * 128 * 2);
    float* bQKV = (float*)alloc((size_t)LL * 384 * 4);
    u16* WtO   = (u16*)alloc((size_t)LL * 128 * 128 * 2);
    u16* WtF1  = (u16*)alloc((size_t)LL * 256 * 128 * 2);
    u16* WtF2  = (u16*)alloc((size_t)LL * 128 * 256 * 2);
    u16* hb    = (u16*)alloc((size_t)NN * DD * 2);
    u16* Qb    = (u16*)alloc((size_t)NN * 128 * 2);
    u16* Kb    = (u16*)alloc((size_t)NN * 128 * 2);
    unsigned char* Vb = (unsigned char*)alloc((size_t)NN * 128);
    u16* att   = (u16*)alloc((size_t)NN * DD * 2);
    u16* hmid  = (u16*)alloc((size_t)NN * DD * 2);

    hipMemsetAsync(cnt, 0, (size_t)NN * 4, stream);
    prep_kernel<<<PREP_BLOCKS, 256, 0, stream>>>(dst, cnt, h_in, hb,
                                                 Wq, Wk, Wv, bq, bk, bv, WtQKV, bQKV,
                                                 Wo, W1, W2, WtO, WtF1, WtF2);
    scan_kernel<<<1, 1024, 0, stream>>>(cnt, offs, cur);
    fill_kernel<<<8 * FILL_SUB, 256, 0, stream>>>(src, dst, cur, srcs);

    const int MB = (NN + BM - 1) / BM;     // 391
    const int MB64 = (NN + 63) / 64;       // 782
    const u16* hcur = hb;
    for (int l = 0; l < LL; l++){
        gemm_qkv<<<dim3(MB, 3), 256, 0, stream>>>(hcur, WtQKV + (size_t)l * 384 * 128,
                                                  bQKV + l * 384, Qb, Kb, Vb, NN);
        edge_attn_kernel<<<NN / 4, 256, 0, stream>>>(Qb, Kb, Vb, srcs, offs, att);
        if (l == LL - 1)
            tail_kernel<<<MB64, 256, 0, stream>>>(att, WtO + (size_t)l * 128 * 128, bo + l * 128,
                                                  hcur, ln1_g + l * 128, ln1_b + l * 128,
                                                  WtF1 + (size_t)l * 256 * 128, b1 + l * 256,
                                                  WtF2 + (size_t)l * 128 * 256, b2 + l * 128,
                                                  ln2_g + l * 128, ln2_b + l * 128,
                                                  nullptr, outp, NN);
        else
            tail_kernel<<<MB64, 256, 0, stream>>>(att, WtO + (size_t)l * 128 * 128, bo + l * 128,
                                                  hcur, ln1_g + l * 128, ln1_b + l * 128,
                                                  WtF1 + (size_t)l * 256 * 128, b1 + l * 256,
                                                  WtF2 + (size_t)l * 128 * 256, b2 + l * 128,
                                                  ln2_g + l * 128, ln2_b + l * 128,
                                                  hmid, nullptr, NN);
        hcur = hmid;
    }
}

// Round 17
// 452.052 us; speedup vs baseline: 1.1829x; 1.0138x over previous
//
#include <hip/hip_runtime.h>

#define NN 50000
#define DD 128
#define HH 8
#define EE 1600000
#define LL 2

typedef unsigned short u16;
typedef __attribute__((ext_vector_type(8))) __bf16 bf16x8;
typedef __attribute__((ext_vector_type(4))) float f32x4;
typedef __attribute__((ext_vector_type(2))) float f32x2;

__device__ __forceinline__ float bf2f(u16 u){
    return __uint_as_float(((unsigned int)u) << 16);
}
__device__ __forceinline__ u16 f2bf(float f){
    unsigned int x = __float_as_uint(f);
    x = x + 0x7fff + ((x >> 16) & 1);   // round-to-nearest-even
    return (u16)(x >> 16);
}

// async global->LDS, 16B per lane, linear dest (wave base + lane*16)
__device__ __forceinline__ void async16(const u16* g, u16* l){
    __builtin_amdgcn_global_load_lds(
        (const __attribute__((address_space(1))) unsigned int*)(const void*)g,
        (__attribute__((address_space(3))) unsigned int*)(void*)l, 16, 0, 0);
}

// ---------------- mega-prep: count | f2b4 | qkvpack | wprep in ONE launch ----------------
#define FILL_SUB 128
#define PREP_BLOCKS (1024 + 6250 + 384 + 768)

__global__ __launch_bounds__(256) void prep_kernel(
        const int* __restrict__ dst, int* __restrict__ cnt,
        const float* __restrict__ h_in, u16* __restrict__ hb,
        const float* __restrict__ Wq, const float* __restrict__ Wk, const float* __restrict__ Wv,
        const float* __restrict__ bq, const float* __restrict__ bk, const float* __restrict__ bv,
        u16* __restrict__ WtQKV, float* __restrict__ bQKV,
        const float* __restrict__ Wo, const float* __restrict__ W1, const float* __restrict__ W2,
        u16* __restrict__ WtO, u16* __restrict__ WtF1, u16* __restrict__ WtF2){
    int b = blockIdx.x;
    if (b < 1024){
        int slice = b & 7;
        int sub = b >> 3;
        int lo = slice * (NN / 8), hi = lo + (NN / 8);
        for (int e = sub * 256 + threadIdx.x; e < EE; e += FILL_SUB * 256){
            int d = dst[e];
            if (d >= lo && d < hi) atomicAdd(&cnt[d], 1);
        }
        return;
    }
    b -= 1024;
    if (b < 6250){
        int i = b * 256 + threadIdx.x;
        if (i < NN * DD / 4){
            float4 v = ((const float4*)h_in)[i];
            ushort4 o;
            o.x = f2bf(v.x); o.y = f2bf(v.y); o.z = f2bf(v.z); o.w = f2bf(v.w);
            ((ushort4*)hb)[i] = o;
        }
        return;
    }
    b -= 6250;
    if (b < 384){
        int l = b / 192;
        int idx = (b % 192) * 256 + threadIdx.x;
        if (idx < 384 * 128){
            int n = idx >> 7, k = idx & 127;
            const float* W = (n < 128) ? Wq : (n < 256) ? Wk : Wv;
            int nc = n & 127;
            WtQKV[(size_t)l * 384 * 128 + idx] = f2bf(W[(size_t)l * 128 * 128 + k * 128 + nc]);
            if (k == 0){
                const float* bb = (n < 128) ? bq : (n < 256) ? bk : bv;
                bQKV[l * 384 + n] = bb[l * 128 + nc];
            }
        }
        return;
    }
    b -= 384;
    {
        int which = b / 256;
        int rem = b % 256;
        int l = rem / 128;
        int idx = (rem % 128) * 256 + threadIdx.x;
        const float* in; u16* out; int R, C;
        if (which == 0){ in = Wo; out = WtO; R = 128; C = 128; }
        else if (which == 1){ in = W1; out = WtF1; R = 128; C = 256; }
        else { in = W2; out = WtF2; R = 256; C = 128; }
        int total = R * C;
        if (idx < total){
            size_t mat = (size_t)l * total;
            int r = idx / C, c = idx % C;
            out[mat + (size_t)c * R + r] = f2bf(in[mat + idx]);
        }
    }
}

// ---------------- CSR scan + fill ----------------
__global__ __launch_bounds__(1024) void scan_kernel(const int* __restrict__ cnt,
                                                    int* __restrict__ offs, int* __restrict__ cur){
    __shared__ int wsum[16];
    __shared__ int carry_s;
    __shared__ int ctot_s;
    int t = threadIdx.x, lane = t & 63, w = t >> 6;
    if (t == 0){ offs[0] = 0; cur[0] = 0; carry_s = 0; }
    __syncthreads();
    const int N4 = NN / 4;
    for (int base = 0; base < N4; base += 1024){
        int i4 = base + t;
        int4 x = (i4 < N4) ? ((const int4*)cnt)[i4] : make_int4(0, 0, 0, 0);
        int s1 = x.x, s2 = s1 + x.y, s3 = s2 + x.z, s4 = s3 + x.w;
        int v = s4;
        #pragma unroll
        for (int d = 1; d < 64; d <<= 1){ int u = __shfl_up(v, d); if (lane >= d) v += u; }
        if (lane == 63) wsum[w] = v;
        __syncthreads();
        if (t < 16){
            int sv = wsum[t];
            int iv = sv;
            #pragma unroll
            for (int d = 1; d < 16; d <<= 1){ int u = __shfl_up(iv, d); if (t >= d) iv += u; }
            wsum[t] = iv - sv;
            if (t == 15) ctot_s = iv;
        }
        __syncthreads();
        int excl = carry_s + wsum[w] + (v - s4);
        if (i4 < N4){
            int o = 4 * i4;
            offs[o + 1] = excl + s1;  cur[o + 1] = excl + s1;
            offs[o + 2] = excl + s2;  cur[o + 2] = excl + s2;
            offs[o + 3] = excl + s3;  cur[o + 3] = excl + s3;
            offs[o + 4] = excl + s4;  cur[o + 4] = excl + s4;
        }
        __syncthreads();
        if (t == 0) carry_s += ctot_s;
        __syncthreads();
    }
}

__global__ __launch_bounds__(256) void fill_kernel(const int* __restrict__ src, const int* __restrict__ dst,
                                                   int* __restrict__ cur, int* __restrict__ srcs){
    int slice = blockIdx.x & 7;
    int sub = blockIdx.x >> 3;
    int lo = slice * (NN / 8), hi = lo + (NN / 8);
    for (int e = sub * 256 + threadIdx.x; e < EE; e += FILL_SUB * 256){
        int d = dst[e];
        if (d >= lo && d < hi){
            int p = atomicAdd(&cur[d], 1);
            srcs[p] = src[e];
        }
    }
}

// ================= GEMM core helpers (global_load_lds + XOR swizzle) ==========
#define BM 128
#define LDC 136

__device__ __forceinline__ void stage_tile(const u16* __restrict__ A, const u16* __restrict__ Wt,
                                           u16* As, u16* Bs, int M, int K, int m0, int n0, int k0,
                                           int w, int lane){
    int lr = lane >> 3;
    int swz = ((lane & 7) ^ lr) * 8;
    #pragma unroll
    for (int p = 0; p < 4; p++){
        int s = p * 4 + w;
        int ga = m0 + s * 8 + lr;
        if (ga >= M) ga = M - 1;
        async16(A + (size_t)ga * K + k0 + swz, As + s * 512);
        async16(Wt + (size_t)(n0 + s * 8 + lr) * K + k0 + swz, Bs + s * 512);
    }
}

__device__ __forceinline__ void mfma_tiles(const u16* As, const u16* Bs, f32x4 (&acc)[4][4],
                                           int wm, int wn, int l15, int hi){
    #pragma unroll
    for (int ks = 0; ks < 2; ks++){
        bf16x8 a[4], b[4];
        int ca = ((ks * 4 + hi) ^ (l15 & 7)) * 8;
        #pragma unroll
        for (int i = 0; i < 4; i++){
            a[i] = *(const bf16x8*)(As + (wm * 64 + i * 16 + l15) * 64 + ca);
            b[i] = *(const bf16x8*)(Bs + (wn * 64 + i * 16 + l15) * 64 + ca);
        }
        #pragma unroll
        for (int mi = 0; mi < 4; mi++)
            #pragma unroll
            for (int ni = 0; ni < 4; ni++)
                acc[mi][ni] = __builtin_amdgcn_mfma_f32_16x16x32_bf16(a[mi], b[ni], acc[mi][ni], 0, 0, 0);
    }
}

#define GEMM_LOOP(K)                                                          \
    for (int k0 = 0; k0 < (K); k0 += 64){                                     \
        __syncthreads();                                                      \
        stage_tile(A, Wt, As, Bs, M, (K), m0, n0, k0, w, lane);               \
        asm volatile("s_waitcnt vmcnt(0)" ::: "memory");                      \
        __syncthreads();                                                      \
        mfma_tiles(As, Bs, acc, wm, wn, l15, hi);                             \
    }

// QKV GEMM: n0=0 -> Qb bf16, n0=128 -> Kb bf16, n0=256 -> Vb fp8 e4m3
__global__ __launch_bounds__(256) void gemm_qkv(const u16* __restrict__ A, const u16* __restrict__ Wt,
                                                const float* __restrict__ bias,
                                                u16* __restrict__ Qb, u16* __restrict__ Kb,
                                                unsigned char* __restrict__ Vb, int M){
    __shared__ __align__(16) char smem[128 * LDC * 2];
    u16* As = (u16*)smem;
    u16* Bs = As + 8192;
    u16* Cs = (u16*)smem;

    int tid = threadIdx.x;
    int m0 = blockIdx.x * BM, n0 = blockIdx.y * 128;
    int lane = tid & 63, w = tid >> 6;
    int wm = w >> 1, wn = w & 1;
    int l15 = lane & 15, hi = lane >> 4;

    f32x4 acc[4][4];
    #pragma unroll
    for (int mi = 0; mi < 4; mi++)
        #pragma unroll
        for (int ni = 0; ni < 4; ni++)
            acc[mi][ni] = (f32x4){0.f, 0.f, 0.f, 0.f};

    GEMM_LOOP(128)

    __syncthreads();
    #pragma unroll
    for (int mi = 0; mi < 4; mi++)
        #pragma unroll
        for (int ni = 0; ni < 4; ni++){
            int col = wn * 64 + ni * 16 + l15;
            float bval = bias[n0 + col];
            #pragma unroll
            for (int j = 0; j < 4; j++){
                int rl = wm * 64 + mi * 16 + hi * 4 + j;
                Cs[rl * LDC + col] = f2bf(acc[mi][ni][j] + bval);
            }
        }
    __syncthreads();
    int qrow = tid >> 4, quad = tid & 15;
    if (n0 < 256){
        u16* Tb = (n0 == 0) ? Qb : Kb;
        #pragma unroll
        for (int p = 0; p < 8; p++){
            int rl = p * 16 + qrow;
            int gr = m0 + rl;
            if (gr < M){
                uint4 v = *(const uint4*)(&Cs[rl * LDC + quad * 8]);
                *(uint4*)(Tb + (size_t)gr * 128 + quad * 8) = v;
            }
        }
    } else {
        #pragma unroll
        for (int p = 0; p < 8; p++){
            int rl = p * 16 + qrow;
            int gr = m0 + rl;
            if (gr < M){
                uint4 v = *(const uint4*)(&Cs[rl * LDC + quad * 8]);
                float f0 = bf2f((u16)(v.x & 0xffff)), f1 = bf2f((u16)(v.x >> 16));
                float f2 = bf2f((u16)(v.y & 0xffff)), f3 = bf2f((u16)(v.y >> 16));
                float f4 = bf2f((u16)(v.z & 0xffff)), f5 = bf2f((u16)(v.z >> 16));
                float f6 = bf2f((u16)(v.w & 0xffff)), f7 = bf2f((u16)(v.w >> 16));
                unsigned int w0 = __builtin_amdgcn_cvt_pk_fp8_f32(f0, f1, 0u, false);
                w0 = __builtin_amdgcn_cvt_pk_fp8_f32(f2, f3, w0, true);
                unsigned int w1 = __builtin_amdgcn_cvt_pk_fp8_f32(f4, f5, 0u, false);
                w1 = __builtin_amdgcn_cvt_pk_fp8_f32(f6, f7, w1, true);
                *(uint2*)(Vb + (size_t)gr * 128 + quad * 8) = make_uint2(w0, w1);
            }
        }
    }
}

// ================= layer tail: O-proj+LN1+FFN1+relu+FFN2+LN2, one 64-row tile =================
__global__ __launch_bounds__(256) void tail_kernel(const u16* __restrict__ att,
                                                   const u16* __restrict__ WtO, const float* __restrict__ bo,
                                                   const u16* __restrict__ resid,
                                                   const float* __restrict__ g1, const float* __restrict__ b1v,
                                                   const u16* __restrict__ W1t, const float* __restrict__ b1f,
                                                   const u16* __restrict__ W2t, const float* __restrict__ b2f,
                                                   const float* __restrict__ g2, const float* __restrict__ b2v,
                                                   u16* __restrict__ out_bf, float* __restrict__ out_f,
                                                   int M){
    __shared__ __align__(16) u16 h1c[8192];     // 16KB: 2 chunks [64][64] (swizzled)
    __shared__ __align__(16) u16 mid[16384];    // 32KB: 4 chunks [64][64] (swizzled)
    __shared__ __align__(16) u16 Bs[8192];      // 16KB B staging
    __shared__ float ps[2][64];
    __shared__ float pss[2][64];
    u16* AsO = mid;                             // O-proj A staging overlay (8KB)

    int tid = threadIdx.x, lane = tid & 63, w = tid >> 6;
    int l15 = lane & 15, hi = lane >> 4;
    int wm = w >> 1, wn = w & 1;
    int m0 = blockIdx.x * 64;
    int lr = lane >> 3;
    int swz = ((lane & 7) ^ lr) * 8;

    // ---- O-proj ----
    f32x4 acc0[2][4];
    #pragma unroll
    for (int mi = 0; mi < 2; mi++)
        #pragma unroll
        for (int ni = 0; ni < 4; ni++)
            acc0[mi][ni] = (f32x4){0.f, 0.f, 0.f, 0.f};

    for (int kh = 0; kh < 2; kh++){
        __syncthreads();
        #pragma unroll
        for (int p = 0; p < 2; p++){
            int s = p * 4 + w;
            int ga = m0 + s * 8 + lr;
            if (ga >= M) ga = M - 1;
            async16(att + (size_t)ga * 128 + kh * 64 + swz, AsO + s * 512);
        }
        #pragma unroll
        for (int p = 0; p < 4; p++){
            int s = p * 4 + w;
            int row = s * 8 + lr;
            async16(WtO + (size_t)row * 128 + kh * 64 + swz, Bs + s * 512);
        }
        asm volatile("s_waitcnt vmcnt(0)" ::: "memory");
        __syncthreads();
        #pragma unroll
        for (int ks = 0; ks < 2; ks++){
            int ca = ((ks * 4 + hi) ^ (l15 & 7)) * 8;
            bf16x8 a[2], bb[4];
            #pragma unroll
            for (int i = 0; i < 2; i++)
                a[i] = *(const bf16x8*)(AsO + (wm * 32 + i * 16 + l15) * 64 + ca);
            #pragma unroll
            for (int i = 0; i < 4; i++)
                bb[i] = *(const bf16x8*)(Bs + (wn * 64 + i * 16 + l15) * 64 + ca);
            #pragma unroll
            for (int mi = 0; mi < 2; mi++)
                #pragma unroll
                for (int ni = 0; ni < 4; ni++)
                    acc0[mi][ni] = __builtin_amdgcn_mfma_f32_16x16x32_bf16(a[mi], bb[ni], acc0[mi][ni], 0, 0, 0);
        }
    }

    // ---- LN1 -> h1c ----
    {
        float gc[4], bc[4], bv[4];
        #pragma unroll
        for (int ni = 0; ni < 4; ni++){
            int col = wn * 64 + ni * 16 + l15;
            gc[ni] = g1[col]; bc[ni] = b1v[col]; bv[ni] = bo[col];
        }
        #pragma unroll
        for (int mi = 0; mi < 2; mi++)
            #pragma unroll
            for (int j = 0; j < 4; j++){
                int row = wm * 32 + mi * 16 + hi * 4 + j;
                int gr = m0 + row;
                float s = 0.f, ss = 0.f;
                #pragma unroll
                for (int ni = 0; ni < 4; ni++){
                    int col = wn * 64 + ni * 16 + l15;
                    float x = acc0[mi][ni][j] + bv[ni];
                    if (gr < M) x += bf2f(resid[(size_t)gr * 128 + col]);
                    acc0[mi][ni][j] = x;
                    s += x; ss += x * x;
                }
                #pragma unroll
                for (int d = 1; d < 16; d <<= 1){
                    s  += __shfl_xor(s, d);
                    ss += __shfl_xor(ss, d);
                }
                if (l15 == 0){ ps[wn][row] = s; pss[wn][row] = ss; }
            }
        __syncthreads();
        #pragma unroll
        for (int mi = 0; mi < 2; mi++)
            #pragma unroll
            for (int j = 0; j < 4; j++){
                int row = wm * 32 + mi * 16 + hi * 4 + j;
                float s = ps[0][row] + ps[1][row];
                float ss = pss[0][row] + pss[1][row];
                float mean = s * (1.f / 128.f);
                float var = ss * (1.f / 128.f) - mean * mean;
                float r = rsqrtf(var + 1e-5f);
                #pragma unroll
                for (int ni = 0; ni < 4; ni++){
                    int kcol = ni * 16 + l15;
                    float o = (acc0[mi][ni][j] - mean) * r * gc[ni] + bc[ni];
                    h1c[wn * 4096 + row * 64 + (((kcol >> 3) ^ (row & 7)) * 8 + (kcol & 7))] = f2bf(o);
                }
            }
    }

    // ---- FFN1 ----
    f32x4 acc1[2][2][4];
    #pragma unroll
    for (int nh = 0; nh < 2; nh++)
        #pragma unroll
        for (int mi = 0; mi < 2; mi++)
            #pragma unroll
            for (int ni = 0; ni < 4; ni++)
                acc1[nh][mi][ni] = (f32x4){0.f, 0.f, 0.f, 0.f};

    for (int nh = 0; nh < 2; nh++){
        for (int kh = 0; kh < 2; kh++){
            __syncthreads();
            #pragma unroll
            for (int p = 0; p < 4; p++){
                int s = p * 4 + w;
                int row = s * 8 + lr;
                async16(W1t + (size_t)(nh * 128 + row) * 128 + kh * 64 + swz, Bs + s * 512);
            }
            asm volatile("s_waitcnt vmcnt(0)" ::: "memory");
            __syncthreads();
            #pragma unroll
            for (int ks = 0; ks < 2; ks++){
                int ca = ((ks * 4 + hi) ^ (l15 & 7)) * 8;
                bf16x8 a[2], bb[4];
                #pragma unroll
                for (int i = 0; i < 2; i++)
                    a[i] = *(const bf16x8*)(h1c + kh * 4096 + (wm * 32 + i * 16 + l15) * 64 + ca);
                #pragma unroll
                for (int i = 0; i < 4; i++)
                    bb[i] = *(const bf16x8*)(Bs + (wn * 64 + i * 16 + l15) * 64 + ca);
                #pragma unroll
                for (int mi = 0; mi < 2; mi++)
                    #pragma unroll
                    for (int ni = 0; ni < 4; ni++)
                        acc1[nh][mi][ni] = __builtin_amdgcn_mfma_f32_16x16x32_bf16(a[mi], bb[ni], acc1[nh][mi][ni], 0, 0, 0);
            }
        }
    }
    __syncthreads();
    #pragma unroll
    for (int nh = 0; nh < 2; nh++)
        #pragma unroll
        for (int ni = 0; ni < 4; ni++){
            float bv = b1f[nh * 128 + wn * 64 + ni * 16 + l15];
            int kcol = ni * 16 + l15;
            int chunk = nh * 2 + wn;
            #pragma unroll
            for (int mi = 0; mi < 2; mi++)
                #pragma unroll
                for (int j = 0; j < 4; j++){
                    int row = wm * 32 + mi * 16 + hi * 4 + j;
                    float v = fmaxf(acc1[nh][mi][ni][j] + bv, 0.f);
                    mid[chunk * 4096 + row * 64 + (((kcol >> 3) ^ (row & 7)) * 8 + (kcol & 7))] = f2bf(v);
                }
        }

    // ---- FFN2 ----
    f32x4 acc2[2][4];
    #pragma unroll
    for (int mi = 0; mi < 2; mi++)
        #pragma unroll
        for (int ni = 0; ni < 4; ni++)
            acc2[mi][ni] = (f32x4){0.f, 0.f, 0.f, 0.f};

    for (int kt = 0; kt < 4; kt++){
        __syncthreads();
        #pragma unroll
        for (int p = 0; p < 4; p++){
            int s = p * 4 + w;
            int row = s * 8 + lr;
            async16(W2t + (size_t)row * 256 + kt * 64 + swz, Bs + s * 512);
        }
        asm volatile("s_waitcnt vmcnt(0)" ::: "memory");
        __syncthreads();
        #pragma unroll
        for (int ks = 0; ks < 2; ks++){
            int ca = ((ks * 4 + hi) ^ (l15 & 7)) * 8;
            bf16x8 a[2], bb[4];
            #pragma unroll
            for (int i = 0; i < 2; i++)
                a[i] = *(const bf16x8*)(mid + kt * 4096 + (wm * 32 + i * 16 + l15) * 64 + ca);
            #pragma unroll
            for (int i = 0; i < 4; i++)
                bb[i] = *(const bf16x8*)(Bs + (wn * 64 + i * 16 + l15) * 64 + ca);
            #pragma unroll
            for (int mi = 0; mi < 2; mi++)
                #pragma unroll
                for (int ni = 0; ni < 4; ni++)
                    acc2[mi][ni] = __builtin_amdgcn_mfma_f32_16x16x32_bf16(a[mi], bb[ni], acc2[mi][ni], 0, 0, 0);
        }
    }

    // ---- LN2 (resid = h1 from LDS) ----
    float gc2[4], bc2[4], bv2[4];
    #pragma unroll
    for (int ni = 0; ni < 4; ni++){
        int col = wn * 64 + ni * 16 + l15;
        gc2[ni] = g2[col]; bc2[ni] = b2v[col]; bv2[ni] = b2f[col];
    }
    __syncthreads();
    #pragma unroll
    for (int mi = 0; mi < 2; mi++)
        #pragma unroll
        for (int j = 0; j < 4; j++){
            int row = wm * 32 + mi * 16 + hi * 4 + j;
            float s = 0.f, ss = 0.f;
            #pragma unroll
            for (int ni = 0; ni < 4; ni++){
                int kcol = ni * 16 + l15;
                float h1v = bf2f(h1c[wn * 4096 + row * 64 + (((kcol >> 3) ^ (row & 7)) * 8 + (kcol & 7))]);
                float x = acc2[mi][ni][j] + bv2[ni] + h1v;
                acc2[mi][ni][j] = x;
                s += x; ss += x * x;
            }
            #pragma unroll
            for (int d = 1; d < 16; d <<= 1){
                s  += __shfl_xor(s, d);
                ss += __shfl_xor(ss, d);
            }
            if (l15 == 0){ ps[wn][row] = s; pss[wn][row] = ss; }
        }
    __syncthreads();

    #pragma unroll
    for (int mi = 0; mi < 2; mi++)
        #pragma unroll
        for (int j = 0; j < 4; j++){
            int row = wm * 32 + mi * 16 + hi * 4 + j;
            int gr = m0 + row;
            if (gr >= M) continue;
            float s = ps[0][row] + ps[1][row];
            float ss = pss[0][row] + pss[1][row];
            float mean = s * (1.f / 128.f);
            float var = ss * (1.f / 128.f) - mean * mean;
            float r = rsqrtf(var + 1e-5f);
            #pragma unroll
            for (int ni = 0; ni < 4; ni++){
                int col = wn * 64 + ni * 16 + l15;
                float o = (acc2[mi][ni][j] - mean) * r * gc2[ni] + bc2[ni];
                if (out_f) out_f[(size_t)gr * 128 + col] = o;
                else       out_bf[(size_t)gr * 128 + col] = f2bf(o);
            }
        }
}

// ---------------- edge attention: bf16 K (8B) + fp8 V (4B); srcs software-pipelined ----------------
__global__ __launch_bounds__(256) void edge_attn_kernel(const u16* __restrict__ Qb,
                                                        const u16* __restrict__ Kb,
                                                        const unsigned char* __restrict__ Vb,
                                                        const int* __restrict__ srcs,
                                                        const int* __restrict__ offs,
                                                        u16* __restrict__ att){
    int n = blockIdx.x * 4 + (threadIdx.x >> 6);
    if (n >= NN) return;
    int lane = threadIdx.x & 63;
    int laneh = lane & 31;
    int half = lane >> 5;

    float q0, q1, q2, q3;
    {
        uint2 qv = *(const uint2*)(Qb + (size_t)n * 128 + 4 * laneh);
        q0 = bf2f((u16)(qv.x & 0xffff)); q1 = bf2f((u16)(qv.x >> 16));
        q2 = bf2f((u16)(qv.y & 0xffff)); q3 = bf2f((u16)(qv.y >> 16));
    }
    const u16* kbase = Kb + 4 * laneh;
    const unsigned char* vbase = Vb + 4 * laneh;

    float w0 = 0.f, w1 = 0.f, w2 = 0.f, w3 = 0.f, z = 0.f;
    const float CS = 0.25f * 1.44269504f;

    auto proc = [&](uint2 kk, unsigned int vv, float gate){
        float k0 = bf2f((u16)(kk.x & 0xffff)), k1 = bf2f((u16)(kk.x >> 16));
        float k2 = bf2f((u16)(kk.y & 0xffff)), k3 = bf2f((u16)(kk.y >> 16));
        float p = q0 * k0 + q1 * k1 + q2 * k2 + q3 * k3;
        p += __shfl_xor(p, 1);
        p += __shfl_xor(p, 2);
        p = __builtin_amdgcn_fmed3f(p, -20.f, 20.f);
        float sc = __builtin_amdgcn_exp2f(p * CS) * gate;
        f32x2 vl = __builtin_amdgcn_cvt_pk_f32_fp8(vv, false);
        f32x2 vh = __builtin_amdgcn_cvt_pk_f32_fp8(vv, true);
        w0 += sc * vl[0]; w1 += sc * vl[1]; w2 += sc * vh[0]; w3 += sc * vh[1];
        z += sc;
    };

    int e0 = offs[n], e1 = offs[n + 1];
    int i = e0;
    int sA[8];
    bool haveA = false;
    if (i + 15 < e1){
        #pragma unroll
        for (int u = 0; u < 8; u++) sA[u] = srcs[i + 2 * u + half];
        haveA = true;
    }
    // steady state: prefetch next group's srcs before consuming current group's KV
    for (; i + 31 < e1; i += 16){
        int sB[8];
        #pragma unroll
        for (int u = 0; u < 8; u++) sB[u] = srcs[i + 16 + 2 * u + half];
        uint2 kk[8];
        unsigned int vv[8];
        #pragma unroll
        for (int u = 0; u < 8; u++){
            kk[u] = *(const uint2*)(kbase + (size_t)sA[u] * 128);
            vv[u] = *(const unsigned int*)(vbase + (size_t)sA[u] * 128);
        }
        #pragma unroll
        for (int u = 0; u < 8; u++) proc(kk[u], vv[u], 1.f);
        #pragma unroll
        for (int u = 0; u < 8; u++) sA[u] = sB[u];
    }
    // last full group (srcs already in sA)
    if (haveA && i + 15 < e1){
        uint2 kk[8];
        unsigned int vv[8];
        #pragma unroll
        for (int u = 0; u < 8; u++){
            kk[u] = *(const uint2*)(kbase + (size_t)sA[u] * 128);
            vv[u] = *(const unsigned int*)(vbase + (size_t)sA[u] * 128);
        }
        #pragma unroll
        for (int u = 0; u < 8; u++) proc(kk[u], vv[u], 1.f);
        i += 16;
    }
    for (; i + 1 < e1; i += 2){
        int s = srcs[i + half];
        proc(*(const uint2*)(kbase + (size_t)s * 128),
             *(const unsigned int*)(vbase + (size_t)s * 128), 1.f);
    }
    if (i < e1){
        int s = srcs[i];
        proc(*(const uint2*)(kbase + (size_t)s * 128),
             *(const unsigned int*)(vbase + (size_t)s * 128), half ? 0.f : 1.f);
    }

    w0 += __shfl_xor(w0, 32); w1 += __shfl_xor(w1, 32);
    w2 += __shfl_xor(w2, 32); w3 += __shfl_xor(w3, 32);
    z  += __shfl_xor(z, 32);

    if (!half){
        float inv = 1.f / (z + 1e-6f);
        unsigned int oA = (unsigned int)f2bf(w0 * inv) | ((unsigned int)f2bf(w1 * inv) << 16);
        unsigned int oB = (unsigned int)f2bf(w2 * inv) | ((unsigned int)f2bf(w3 * inv) << 16);
        *(uint2*)(att + (size_t)n * DD + 4 * laneh) = make_uint2(oA, oB);
    }
}

// ---------------- host orchestration ----------------
extern "C" void kernel_launch(void* const* d_in, const int* in_sizes, int n_in,
                              void* d_out, int out_size, void* d_ws, size_t ws_size,
                              hipStream_t stream){
    const float* h_in = (const float*)d_in[0];
    const int* src  = (const int*)d_in[1];
    const int* dst  = (const int*)d_in[2];
    const float* Wq = (const float*)d_in[3];
    const float* bq = (const float*)d_in[4];
    const float* Wk = (const float*)d_in[5];
    const float* bk = (const float*)d_in[6];
    const float* Wv = (const float*)d_in[7];
    const float* bv = (const float*)d_in[8];
    const float* Wo = (const float*)d_in[9];
    const float* bo = (const float*)d_in[10];
    const float* W1 = (const float*)d_in[11];
    const float* b1 = (const float*)d_in[12];
    const float* W2 = (const float*)d_in[13];
    const float* b2 = (const float*)d_in[14];
    const float* ln1_g = (const float*)d_in[15];
    const float* ln1_b = (const float*)d_in[16];
    const float* ln2_g = (const float*)d_in[17];
    const float* ln2_b = (const float*)d_in[18];
    float* outp = (float*)d_out;

    char* ws = (char*)d_ws;
    auto alloc = [&](size_t bytes) -> char* {
        char* p = ws;
        ws += (bytes + 255) & ~(size_t)255;
        return p;
    };
    int* cnt   = (int*)alloc((size_t)NN * 4);
    int* offs  = (int*)alloc((size_t)(NN + 1) * 4);
    int* cur   = (int*)alloc((size_t)(NN + 1) * 4);
    int* srcs  = (int*)alloc((size_t)EE * 4);
    u16* WtQKV = (u16*)alloc((size_t)LL * 384 * 128 * 2);
    float* bQKV = (float*)alloc((size_t)LL * 384 * 4);
    u16* WtO   = (u16*)alloc((size_t)LL * 128 * 128 * 2);
    u16* WtF1  = (u16*)alloc((size_t)LL * 256 * 128 * 2);
    u16* WtF2  = (u16*)alloc((size_t)LL * 128 * 256 * 2);
    u16* hb    = (u16*)alloc((size_t)NN * DD * 2);
    u16* Qb    = (u16*)alloc((size_t)NN * 128 * 2);
    u16* Kb    = (u16*)alloc((size_t)NN * 128 * 2);
    unsigned char* Vb = (unsigned char*)alloc((size_t)NN * 128);
    u16* att   = (u16*)alloc((size_t)NN * DD * 2);
    u16* hmid  = (u16*)alloc((size_t)NN * DD * 2);

    hipMemsetAsync(cnt, 0, (size_t)NN * 4, stream);
    prep_kernel<<<PREP_BLOCKS, 256, 0, stream>>>(dst, cnt, h_in, hb,
                                                 Wq, Wk, Wv, bq, bk, bv, WtQKV, bQKV,
                                                 Wo, W1, W2, WtO, WtF1, WtF2);
    scan_kernel<<<1, 1024, 0, stream>>>(cnt, offs, cur);
    fill_kernel<<<8 * FILL_SUB, 256, 0, stream>>>(src, dst, cur, srcs);

    const int MB = (NN + BM - 1) / BM;     // 391
    const int MB64 = (NN + 63) / 64;       // 782
    const u16* hcur = hb;
    for (int l = 0; l < LL; l++){
        gemm_qkv<<<dim3(MB, 3), 256, 0, stream>>>(hcur, WtQKV + (size_t)l * 384 * 128,
                                                  bQKV + l * 384, Qb, Kb, Vb, NN);
        edge_attn_kernel<<<NN / 4, 256, 0, stream>>>(Qb, Kb, Vb, srcs, offs, att);
        if (l == LL - 1)
            tail_kernel<<<MB64, 256, 0, stream>>>(att, WtO + (size_t)l * 128 * 128, bo + l * 128,
                                                  hcur, ln1_g + l * 128, ln1_b + l * 128,
                                                  WtF1 + (size_t)l * 256 * 128, b1 + l * 256,
                                                  WtF2 + (size_t)l * 128 * 256, b2 + l * 128,
                                                  ln2_g + l * 128, ln2_b + l * 128,
                                                  nullptr, outp, NN);
        else
            tail_kernel<<<MB64, 256, 0, stream>>>(att, WtO + (size_t)l * 128 * 128, bo + l * 128,
                                                  hcur, ln1_g + l * 128, ln1_b + l * 128,
                                                  WtF1 + (size_t)l * 256 * 128, b1 + l * 256,
                                                  WtF2 + (size_t)l * 128 * 256, b2 + l * 128,
                                                  ln2_g + l * 128, ln2_b + l * 128,
                                                  hmid, nullptr, NN);
        hcur = hmid;
    }
}